// Round 9
// baseline (669.263 us; speedup 1.0000x reference)
//
#include <hip/hip_runtime.h>

#define NN 50000
#define NE 800000
#define DD 128

typedef __attribute__((ext_vector_type(8))) short short8;
typedef __attribute__((ext_vector_type(4))) float f32x4;

__device__ inline unsigned short f2bf_rne(float f) {
  unsigned u = __float_as_uint(f);
  u += 0x7FFF + ((u >> 16) & 1);
  return (unsigned short)(u >> 16);
}
__device__ inline float bf2f(unsigned short h) {
  return __uint_as_float(((unsigned)h) << 16);
}

// ------------------------------------------------- CSR build: histogram
__global__ __launch_bounds__(256) void hist_dst(const int* __restrict__ dst,
                                                int* __restrict__ cnt) {
  int e = blockIdx.x * 256 + threadIdx.x;
  if (e < NE) atomicAdd(&cnt[dst[e]], 1);
}

// ------------------------------------------------- CSR build: scan (1 block)
__global__ __launch_bounds__(1024) void scan_nodes(const int* __restrict__ cnt,
                                                   int* __restrict__ offs,
                                                   int* __restrict__ cursor) {
  __shared__ int wsum[16];
  __shared__ int wpre[16];
  const int t = threadIdx.x;
  const int lane = t & 63, wv = t >> 6;
  int carry = 0;
  for (int base = 0; base < NN; base += 8192) {
    const int i0 = base + t * 8;
    int4 a = make_int4(0, 0, 0, 0), b = make_int4(0, 0, 0, 0);
    if (i0 + 8 <= NN) {
      a = *(const int4*)(cnt + i0);
      b = *(const int4*)(cnt + i0 + 4);
    } else if (i0 < NN) {
      int tmp[8];
      for (int j = 0; j < 8; ++j) tmp[j] = (i0 + j < NN) ? cnt[i0 + j] : 0;
      a = make_int4(tmp[0], tmp[1], tmp[2], tmp[3]);
      b = make_int4(tmp[4], tmp[5], tmp[6], tmp[7]);
    }
    const int own = a.x + a.y + a.z + a.w + b.x + b.y + b.z + b.w;
    int inc = own;
#pragma unroll
    for (int d = 1; d < 64; d <<= 1) {
      int v = __shfl_up(inc, d, 64);
      if (lane >= d) inc += v;
    }
    if (lane == 63) wsum[wv] = inc;
    __syncthreads();
    if (t < 16) {
      int v = wsum[t];
      int p = v;
#pragma unroll
      for (int d = 1; d < 16; d <<= 1) {
        int u = __shfl_up(p, d, 16);
        if (t >= d) p += u;
      }
      wpre[t] = p - v;
      if (t == 15) wsum[15] = p;
    }
    __syncthreads();
    int run = carry + wpre[wv] + inc - own;
    const int o0 = run,      o1 = o0 + a.x, o2 = o1 + a.y, o3 = o2 + a.z;
    const int o4 = o3 + a.w, o5 = o4 + b.x, o6 = o5 + b.y, o7 = o6 + b.z;
    if (i0 + 8 <= NN) {
      *(int4*)(offs + i0)       = make_int4(o0, o1, o2, o3);
      *(int4*)(offs + i0 + 4)   = make_int4(o4, o5, o6, o7);
      *(int4*)(cursor + i0)     = make_int4(o0, o1, o2, o3);
      *(int4*)(cursor + i0 + 4) = make_int4(o4, o5, o6, o7);
    } else if (i0 < NN) {
      const int o[8] = {o0, o1, o2, o3, o4, o5, o6, o7};
      for (int j = 0; j < 8; ++j)
        if (i0 + j < NN) { offs[i0 + j] = o[j]; cursor[i0 + j] = o[j]; }
    }
    carry += wsum[15];
    __syncthreads();
  }
  if (t == 0) offs[NN] = carry;
}

// ------------------------------------------------- CSR build: fill
__global__ __launch_bounds__(256) void csr_fill(
    const int* __restrict__ src, const int* __restrict__ dst,
    const float* __restrict__ ea, int* __restrict__ cursor,
    int* __restrict__ srcs_s, float* __restrict__ eas_s,
    int* __restrict__ eid_s) {
  int e = blockIdx.x * 256 + threadIdx.x;
  if (e >= NE) return;
  int pos = atomicAdd(&cursor[dst[e]], 1);
  srcs_s[pos] = src[e];
  eas_s[pos] = ea[e];
  eid_s[pos] = e;
}

// ------------------------------------------------- weight prep: transpose + split
__global__ __launch_bounds__(256) void prep_w(
    const float* __restrict__ Wl1, const float* __restrict__ Wl2,
    const float* __restrict__ Wp1,
    unsigned short* __restrict__ WTh, unsigned short* __restrict__ WTl) {
  int tid = blockIdx.x * 256 + threadIdx.x;  // 8 * 16384
  if (tid >= 8 * 16384) return;
  int g = tid >> 14, idx = tid & 16383;
  int n = idx >> 7, k = idx & 127;
  const float* s;
  if (g < 3) s = Wl1 + (size_t)g * 16384;
  else if (g < 6) s = Wl2 + (size_t)(g - 3) * 16384;
  else s = Wp1 + (size_t)(g - 6) * 16384;
  float v = s[k * 128 + n];
  unsigned short hi = f2bf_rne(v);
  WTh[tid] = hi;
  WTl[tid] = f2bf_rne(v - bf2f(hi));
}

// ------------------------------------------------- per-node aggregation
// One node per 32-lane slot (full-grid TLP) + 4-deep gather unroll (MLP).
__global__ __launch_bounds__(256) void aggregate(
    const float* __restrict__ x, const int* __restrict__ offs,
    const int* __restrict__ srcs_s, const float* __restrict__ eas_s,
    const float4* __restrict__ We4, const float4* __restrict__ be4,
    float* __restrict__ out) {
  const int slot = threadIdx.x >> 5, lane = threadIdx.x & 31;
  const int n = blockIdx.x * 8 + slot;
  if (n >= NN) return;
  const float4 wv = We4[lane], bv = be4[lane];
  float4 a0 = ((const float4*)(x + (size_t)n * DD))[lane];
  float4 a1 = make_float4(0.f, 0.f, 0.f, 0.f);
  float4 a2 = make_float4(0.f, 0.f, 0.f, 0.f);
  float4 a3 = make_float4(0.f, 0.f, 0.f, 0.f);
  const int beg = offs[n], end = offs[n + 1];
  int i = beg;
  for (; i + 4 <= end; i += 4) {
    const int s0 = srcs_s[i], s1 = srcs_s[i + 1];
    const int s2 = srcs_s[i + 2], s3 = srcs_s[i + 3];
    const float e0 = eas_s[i], e1 = eas_s[i + 1];
    const float e2 = eas_s[i + 2], e3 = eas_s[i + 3];
    const float4 x0 = ((const float4*)(x + (size_t)s0 * DD))[lane];
    const float4 x1 = ((const float4*)(x + (size_t)s1 * DD))[lane];
    const float4 x2 = ((const float4*)(x + (size_t)s2 * DD))[lane];
    const float4 x3 = ((const float4*)(x + (size_t)s3 * DD))[lane];
    a0.x += fmaxf(fmaf(e0, wv.x, bv.x) + x0.x, 0.f);
    a0.y += fmaxf(fmaf(e0, wv.y, bv.y) + x0.y, 0.f);
    a0.z += fmaxf(fmaf(e0, wv.z, bv.z) + x0.z, 0.f);
    a0.w += fmaxf(fmaf(e0, wv.w, bv.w) + x0.w, 0.f);
    a1.x += fmaxf(fmaf(e1, wv.x, bv.x) + x1.x, 0.f);
    a1.y += fmaxf(fmaf(e1, wv.y, bv.y) + x1.y, 0.f);
    a1.z += fmaxf(fmaf(e1, wv.z, bv.z) + x1.z, 0.f);
    a1.w += fmaxf(fmaf(e1, wv.w, bv.w) + x1.w, 0.f);
    a2.x += fmaxf(fmaf(e2, wv.x, bv.x) + x2.x, 0.f);
    a2.y += fmaxf(fmaf(e2, wv.y, bv.y) + x2.y, 0.f);
    a2.z += fmaxf(fmaf(e2, wv.z, bv.z) + x2.z, 0.f);
    a2.w += fmaxf(fmaf(e2, wv.w, bv.w) + x2.w, 0.f);
    a3.x += fmaxf(fmaf(e3, wv.x, bv.x) + x3.x, 0.f);
    a3.y += fmaxf(fmaf(e3, wv.y, bv.y) + x3.y, 0.f);
    a3.z += fmaxf(fmaf(e3, wv.z, bv.z) + x3.z, 0.f);
    a3.w += fmaxf(fmaf(e3, wv.w, bv.w) + x3.w, 0.f);
  }
  for (; i < end; ++i) {
    const int s0 = srcs_s[i];
    const float e0 = eas_s[i];
    const float4 x0 = ((const float4*)(x + (size_t)s0 * DD))[lane];
    a0.x += fmaxf(fmaf(e0, wv.x, bv.x) + x0.x, 0.f);
    a0.y += fmaxf(fmaf(e0, wv.y, bv.y) + x0.y, 0.f);
    a0.z += fmaxf(fmaf(e0, wv.z, bv.z) + x0.z, 0.f);
    a0.w += fmaxf(fmaf(e0, wv.w, bv.w) + x0.w, 0.f);
  }
  a0.x += a1.x + a2.x + a3.x;
  a0.y += a1.y + a2.y + a3.y;
  a0.z += a1.z + a2.z + a3.z;
  a0.w += a1.w + a2.w + a3.w;
  ((float4*)(out + (size_t)n * DD))[lane] = a0;
}

// ------------------------------------------------- GEMM: B resident in registers
template <bool RELU, bool HASB, bool INPLACE>
__global__ __launch_bounds__(256) void gemm_breg(
    const float* __restrict__ in,
    const unsigned short* __restrict__ Wh, const unsigned short* __restrict__ Wl,
    const float* __restrict__ bias, float* __restrict__ out) {
  const int t = threadIdx.x;
  const int w = t >> 6, l = t & 63;
  const int lr = l & 15, kg = l >> 4;

  short8 Bh[2][4], Bl[2][4];
#pragma unroll
  for (int ct = 0; ct < 2; ++ct)
#pragma unroll
    for (int ks = 0; ks < 4; ++ks) {
      const size_t bo = (size_t)((w * 2 + ct) * 16 + lr) * DD + ks * 32 + kg * 8;
      Bh[ct][ks] = *(const short8*)(Wh + bo);
      Bl[ct][ks] = *(const short8*)(Wl + bo);
    }
  float bv0 = 0.f, bv1 = 0.f;
  if (HASB) {
    bv0 = bias[(w * 2 + 0) * 16 + lr];
    bv1 = bias[(w * 2 + 1) * 16 + lr];
  }

  for (int c = blockIdx.x; c < NN / 16; c += gridDim.x) {
    const float* ap = in + ((size_t)c * 16 + lr) * DD + kg * 8;
    float va[4][8];
#pragma unroll
    for (int ks = 0; ks < 4; ++ks) {
      *(float4*)&va[ks][0] = *(const float4*)(ap + ks * 32);
      *(float4*)&va[ks][4] = *(const float4*)(ap + ks * 32 + 4);
    }
    short8 ah[4], al[4];
#pragma unroll
    for (int ks = 0; ks < 4; ++ks)
#pragma unroll
      for (int j = 0; j < 8; ++j) {
        unsigned short h = f2bf_rne(va[ks][j]);
        ah[ks][j] = (short)h;
        al[ks][j] = (short)f2bf_rne(va[ks][j] - bf2f(h));
      }
    f32x4 acc[2];
    acc[0] = (f32x4){0.f, 0.f, 0.f, 0.f};
    acc[1] = (f32x4){0.f, 0.f, 0.f, 0.f};
#pragma unroll
    for (int ks = 0; ks < 4; ++ks) {
#pragma unroll
      for (int ct = 0; ct < 2; ++ct) {
        acc[ct] = __builtin_amdgcn_mfma_f32_16x16x32_bf16(ah[ks], Bh[ct][ks], acc[ct], 0, 0, 0);
        acc[ct] = __builtin_amdgcn_mfma_f32_16x16x32_bf16(ah[ks], Bl[ct][ks], acc[ct], 0, 0, 0);
        acc[ct] = __builtin_amdgcn_mfma_f32_16x16x32_bf16(al[ks], Bh[ct][ks], acc[ct], 0, 0, 0);
      }
    }
    if (INPLACE) __syncthreads();
    // C layout: col = lane&15, row = (lane>>4)*4 + q
#pragma unroll
    for (int ct = 0; ct < 2; ++ct) {
      const float bb = ct ? bv1 : bv0;
      const int col = (w * 2 + ct) * 16 + lr;
#pragma unroll
      for (int q4 = 0; q4 < 4; ++q4) {
        float v = acc[ct][q4] + bb;
        if (RELU) v = fmaxf(v, 0.f);
        out[((size_t)c * 16 + kg * 4 + q4) * DD + col] = v;
      }
    }
  }
}

// ------------------------------------------------- final edge pass (node-parallel)
// One node per 32-lane slot + 4-deep gather unroll.
__global__ __launch_bounds__(256) void edge_out(
    const float4* __restrict__ P1_4, const float4* __restrict__ P2_4,
    const int* __restrict__ offs, const int* __restrict__ srcs_s,
    const int* __restrict__ eid_s, const float4* __restrict__ Wp2_4,
    const float* __restrict__ bp2, float* __restrict__ out) {
  const int slot = threadIdx.x >> 5, lane = threadIdx.x & 31;
  const int n = blockIdx.x * 8 + slot;
  if (n >= NN) return;
  const float4 w = Wp2_4[lane];
  const float bb = bp2[0];
  const float4 p2 = P2_4[(size_t)n * 32 + lane];
  const int beg = offs[n], end = offs[n + 1];
  int i = beg;
  for (; i + 4 <= end; i += 4) {
    float v[4];
#pragma unroll
    for (int u = 0; u < 4; ++u) {
      const float4 q = P1_4[(size_t)srcs_s[i + u] * 32 + lane];
      v[u] = fmaxf(q.x + p2.x, 0.f) * w.x + fmaxf(q.y + p2.y, 0.f) * w.y
           + fmaxf(q.z + p2.z, 0.f) * w.z + fmaxf(q.w + p2.w, 0.f) * w.w;
    }
#pragma unroll
    for (int m = 16; m >= 1; m >>= 1) {
#pragma unroll
      for (int u = 0; u < 4; ++u) v[u] += __shfl_xor(v[u], m, 64);
    }
    if (lane == 0) {
#pragma unroll
      for (int u = 0; u < 4; ++u) out[eid_s[i + u]] = v[u] + bb;
    }
  }
  for (; i < end; ++i) {
    const float4 q = P1_4[(size_t)srcs_s[i] * 32 + lane];
    float v = fmaxf(q.x + p2.x, 0.f) * w.x + fmaxf(q.y + p2.y, 0.f) * w.y
            + fmaxf(q.z + p2.z, 0.f) * w.z + fmaxf(q.w + p2.w, 0.f) * w.w;
#pragma unroll
    for (int m = 16; m >= 1; m >>= 1) v += __shfl_xor(v, m, 64);
    if (lane == 0) out[eid_s[i]] = v + bb;
  }
}

// ---------------------------------------------------------------- launch
extern "C" void kernel_launch(void* const* d_in, const int* in_sizes, int n_in,
                              void* d_out, int out_size, void* d_ws, size_t ws_size,
                              hipStream_t stream) {
  const float* x_in = (const float*)d_in[0];
  const float* ea   = (const float*)d_in[1];
  const int*   ei   = (const int*)d_in[2];   // integer inputs arrive as int32
  const float* Wl1 = (const float*)d_in[3];
  const float* bl1 = (const float*)d_in[4];
  const float* Wl2 = (const float*)d_in[5];
  const float* bl2 = (const float*)d_in[6];
  const float* We  = (const float*)d_in[7];
  const float* be  = (const float*)d_in[8];
  const float* Wp1 = (const float*)d_in[9];
  const float* bp1 = (const float*)d_in[10];
  const float* Wp2 = (const float*)d_in[11];
  const float* bp2 = (const float*)d_in[12];
  const int* src = ei;
  const int* dst = ei + NE;

  // workspace layout (~62 MB)
  float* bufA   = (float*)d_ws;                    // NN*DD
  float* bufB   = bufA + (size_t)NN * DD;          // NN*DD
  int*   cnt    = (int*)(bufB + (size_t)NN * DD);  // NN
  int*   offs   = cnt + NN;                        // NN+1
  int*   cursor = offs + NN + 1;                   // NN
  int*   srcs_s = cursor + NN;                     // NE
  float* eas_s  = (float*)(srcs_s + NE);           // NE
  int*   eid_s  = (int*)(eas_s + NE);              // NE
  unsigned short* WTh = (unsigned short*)(eid_s + NE);  // 8*16384 bf16
  unsigned short* WTl = WTh + 8 * 16384;                // 8*16384 bf16

  // CSR build + weight prep (per-launch, deterministic)
  hipMemsetAsync(cnt, 0, NN * sizeof(int), stream);
  hist_dst<<<NE / 256, 256, 0, stream>>>(dst, cnt);
  scan_nodes<<<1, 1024, 0, stream>>>(cnt, offs, cursor);
  csr_fill<<<NE / 256, 256, 0, stream>>>(src, dst, ea, cursor, srcs_s, eas_s, eid_s);
  prep_w<<<(8 * 16384 + 255) / 256, 256, 0, stream>>>(Wl1, Wl2, Wp1, WTh, WTl);

  const int GB = 3125;            // gemm grid: 1 chunk/block
  const int AB = (NN + 7) / 8;    // 6250 blocks: 1 node/slot (max TLP)
#define WH(g) (WTh + (size_t)(g) * 16384)
#define WL(g) (WTl + (size_t)(g) * 16384)

  // layer 0: x_in -> bufA -> bufB -> bufA
  aggregate<<<AB, 256, 0, stream>>>(
      x_in, offs, srcs_s, eas_s, (const float4*)We, (const float4*)be, bufA);
  gemm_breg<true, true, false><<<GB, 256, 0, stream>>>(bufA, WH(0), WL(0), bl1, bufB);
  gemm_breg<true, true, false><<<GB, 256, 0, stream>>>(bufB, WH(3), WL(3), bl2, bufA);
  // layer 1
  aggregate<<<AB, 256, 0, stream>>>(
      bufA, offs, srcs_s, eas_s, (const float4*)(We + DD), (const float4*)(be + DD), bufB);
  gemm_breg<true, true, false><<<GB, 256, 0, stream>>>(bufB, WH(1), WL(1), bl1 + DD, bufA);
  gemm_breg<true, true, false><<<GB, 256, 0, stream>>>(bufA, WH(4), WL(4), bl2 + DD, bufB);
  // layer 2
  aggregate<<<AB, 256, 0, stream>>>(
      bufB, offs, srcs_s, eas_s, (const float4*)(We + 2 * DD), (const float4*)(be + 2 * DD), bufA);
  gemm_breg<true, true, false><<<GB, 256, 0, stream>>>(bufA, WH(2), WL(2), bl1 + 2 * DD, bufB);
  gemm_breg<true, true, false><<<GB, 256, 0, stream>>>(bufB, WH(5), WL(5), bl2 + 2 * DD, bufA);
  // predictor: xf = bufA. P2 -> bufB, then P1 in-place -> bufA.
  gemm_breg<false, true, false><<<GB, 256, 0, stream>>>(bufA, WH(7), WL(7), bp1, bufB);
  gemm_breg<false, false, true><<<GB, 256, 0, stream>>>(bufA, WH(6), WL(6), (const float*)nullptr, bufA);
  edge_out<<<AB, 256, 0, stream>>>(
      (const float4*)bufA, (const float4*)bufB, offs, srcs_s, eid_s,
      (const float4*)Wp2, bp2, (float*)d_out);
}

// Round 10
// 533.952 us; speedup vs baseline: 1.2534x; 1.2534x over previous
//
#include <hip/hip_runtime.h>

#define NN 50000
#define NE 800000
#define DD 128

typedef __attribute__((ext_vector_type(8))) short short8;
typedef __attribute__((ext_vector_type(4))) float f32x4;

__device__ inline unsigned short f2bf_rne(float f) {
  unsigned u = __float_as_uint(f);
  u += 0x7FFF + ((u >> 16) & 1);
  return (unsigned short)(u >> 16);
}
__device__ inline float bf2f(unsigned short h) {
  return __uint_as_float(((unsigned)h) << 16);
}

// ------------------------------------------------- CSR build: histogram
__global__ __launch_bounds__(256) void hist_dst(const int* __restrict__ dst,
                                                int* __restrict__ cnt) {
  int e = blockIdx.x * 256 + threadIdx.x;
  if (e < NE) atomicAdd(&cnt[dst[e]], 1);
}

// ------------------------------------------------- CSR build: scan (1 block)
__global__ __launch_bounds__(1024) void scan_nodes(const int* __restrict__ cnt,
                                                   int* __restrict__ offs,
                                                   int* __restrict__ cursor) {
  __shared__ int wsum[16];
  __shared__ int wpre[16];
  const int t = threadIdx.x;
  const int lane = t & 63, wv = t >> 6;
  int carry = 0;
  for (int base = 0; base < NN; base += 8192) {
    const int i0 = base + t * 8;
    int4 a = make_int4(0, 0, 0, 0), b = make_int4(0, 0, 0, 0);
    if (i0 + 8 <= NN) {
      a = *(const int4*)(cnt + i0);
      b = *(const int4*)(cnt + i0 + 4);
    } else if (i0 < NN) {
      int tmp[8];
      for (int j = 0; j < 8; ++j) tmp[j] = (i0 + j < NN) ? cnt[i0 + j] : 0;
      a = make_int4(tmp[0], tmp[1], tmp[2], tmp[3]);
      b = make_int4(tmp[4], tmp[5], tmp[6], tmp[7]);
    }
    const int own = a.x + a.y + a.z + a.w + b.x + b.y + b.z + b.w;
    int inc = own;
#pragma unroll
    for (int d = 1; d < 64; d <<= 1) {
      int v = __shfl_up(inc, d, 64);
      if (lane >= d) inc += v;
    }
    if (lane == 63) wsum[wv] = inc;
    __syncthreads();
    if (t < 16) {
      int v = wsum[t];
      int p = v;
#pragma unroll
      for (int d = 1; d < 16; d <<= 1) {
        int u = __shfl_up(p, d, 16);
        if (t >= d) p += u;
      }
      wpre[t] = p - v;
      if (t == 15) wsum[15] = p;
    }
    __syncthreads();
    int run = carry + wpre[wv] + inc - own;
    const int o0 = run,      o1 = o0 + a.x, o2 = o1 + a.y, o3 = o2 + a.z;
    const int o4 = o3 + a.w, o5 = o4 + b.x, o6 = o5 + b.y, o7 = o6 + b.z;
    if (i0 + 8 <= NN) {
      *(int4*)(offs + i0)       = make_int4(o0, o1, o2, o3);
      *(int4*)(offs + i0 + 4)   = make_int4(o4, o5, o6, o7);
      *(int4*)(cursor + i0)     = make_int4(o0, o1, o2, o3);
      *(int4*)(cursor + i0 + 4) = make_int4(o4, o5, o6, o7);
    } else if (i0 < NN) {
      const int o[8] = {o0, o1, o2, o3, o4, o5, o6, o7};
      for (int j = 0; j < 8; ++j)
        if (i0 + j < NN) { offs[i0 + j] = o[j]; cursor[i0 + j] = o[j]; }
    }
    carry += wsum[15];
    __syncthreads();
  }
  if (t == 0) offs[NN] = carry;
}

// ------------------------------------------------- CSR build: fill
__global__ __launch_bounds__(256) void csr_fill(
    const int* __restrict__ src, const int* __restrict__ dst,
    const float* __restrict__ ea, int* __restrict__ cursor,
    int* __restrict__ srcs_s, float* __restrict__ eas_s,
    int* __restrict__ eid_s) {
  int e = blockIdx.x * 256 + threadIdx.x;
  if (e >= NE) return;
  int pos = atomicAdd(&cursor[dst[e]], 1);
  srcs_s[pos] = src[e];
  eas_s[pos] = ea[e];
  eid_s[pos] = e;
}

// ------------------------------------------------- weight prep: transpose + split
__global__ __launch_bounds__(256) void prep_w(
    const float* __restrict__ Wl1, const float* __restrict__ Wl2,
    const float* __restrict__ Wp1,
    unsigned short* __restrict__ WTh, unsigned short* __restrict__ WTl) {
  int tid = blockIdx.x * 256 + threadIdx.x;  // 8 * 16384
  if (tid >= 8 * 16384) return;
  int g = tid >> 14, idx = tid & 16383;
  int n = idx >> 7, k = idx & 127;
  const float* s;
  if (g < 3) s = Wl1 + (size_t)g * 16384;
  else if (g < 6) s = Wl2 + (size_t)(g - 3) * 16384;
  else s = Wp1 + (size_t)(g - 6) * 16384;
  float v = s[k * 128 + n];
  unsigned short hi = f2bf_rne(v);
  WTh[tid] = hi;
  WTl[tid] = f2bf_rne(v - bf2f(hi));
}

// ------------------------------------------------- per-node aggregation
// One node per 32-lane slot (full-grid TLP) + 4-deep gather unroll (MLP).
__global__ __launch_bounds__(256) void aggregate(
    const float* __restrict__ x, const int* __restrict__ offs,
    const int* __restrict__ srcs_s, const float* __restrict__ eas_s,
    const float4* __restrict__ We4, const float4* __restrict__ be4,
    float* __restrict__ out) {
  const int slot = threadIdx.x >> 5, lane = threadIdx.x & 31;
  const int n = blockIdx.x * 8 + slot;
  if (n >= NN) return;
  const float4 wv = We4[lane], bv = be4[lane];
  float4 a0 = ((const float4*)(x + (size_t)n * DD))[lane];
  float4 a1 = make_float4(0.f, 0.f, 0.f, 0.f);
  float4 a2 = make_float4(0.f, 0.f, 0.f, 0.f);
  float4 a3 = make_float4(0.f, 0.f, 0.f, 0.f);
  const int beg = offs[n], end = offs[n + 1];
  int i = beg;
  for (; i + 4 <= end; i += 4) {
    const int s0 = srcs_s[i], s1 = srcs_s[i + 1];
    const int s2 = srcs_s[i + 2], s3 = srcs_s[i + 3];
    const float e0 = eas_s[i], e1 = eas_s[i + 1];
    const float e2 = eas_s[i + 2], e3 = eas_s[i + 3];
    const float4 x0 = ((const float4*)(x + (size_t)s0 * DD))[lane];
    const float4 x1 = ((const float4*)(x + (size_t)s1 * DD))[lane];
    const float4 x2 = ((const float4*)(x + (size_t)s2 * DD))[lane];
    const float4 x3 = ((const float4*)(x + (size_t)s3 * DD))[lane];
    a0.x += fmaxf(fmaf(e0, wv.x, bv.x) + x0.x, 0.f);
    a0.y += fmaxf(fmaf(e0, wv.y, bv.y) + x0.y, 0.f);
    a0.z += fmaxf(fmaf(e0, wv.z, bv.z) + x0.z, 0.f);
    a0.w += fmaxf(fmaf(e0, wv.w, bv.w) + x0.w, 0.f);
    a1.x += fmaxf(fmaf(e1, wv.x, bv.x) + x1.x, 0.f);
    a1.y += fmaxf(fmaf(e1, wv.y, bv.y) + x1.y, 0.f);
    a1.z += fmaxf(fmaf(e1, wv.z, bv.z) + x1.z, 0.f);
    a1.w += fmaxf(fmaf(e1, wv.w, bv.w) + x1.w, 0.f);
    a2.x += fmaxf(fmaf(e2, wv.x, bv.x) + x2.x, 0.f);
    a2.y += fmaxf(fmaf(e2, wv.y, bv.y) + x2.y, 0.f);
    a2.z += fmaxf(fmaf(e2, wv.z, bv.z) + x2.z, 0.f);
    a2.w += fmaxf(fmaf(e2, wv.w, bv.w) + x2.w, 0.f);
    a3.x += fmaxf(fmaf(e3, wv.x, bv.x) + x3.x, 0.f);
    a3.y += fmaxf(fmaf(e3, wv.y, bv.y) + x3.y, 0.f);
    a3.z += fmaxf(fmaf(e3, wv.z, bv.z) + x3.z, 0.f);
    a3.w += fmaxf(fmaf(e3, wv.w, bv.w) + x3.w, 0.f);
  }
  for (; i < end; ++i) {
    const int s0 = srcs_s[i];
    const float e0 = eas_s[i];
    const float4 x0 = ((const float4*)(x + (size_t)s0 * DD))[lane];
    a0.x += fmaxf(fmaf(e0, wv.x, bv.x) + x0.x, 0.f);
    a0.y += fmaxf(fmaf(e0, wv.y, bv.y) + x0.y, 0.f);
    a0.z += fmaxf(fmaf(e0, wv.z, bv.z) + x0.z, 0.f);
    a0.w += fmaxf(fmaf(e0, wv.w, bv.w) + x0.w, 0.f);
  }
  a0.x += a1.x + a2.x + a3.x;
  a0.y += a1.y + a2.y + a3.y;
  a0.z += a1.z + a2.z + a3.z;
  a0.w += a1.w + a2.w + a3.w;
  ((float4*)(out + (size_t)n * DD))[lane] = a0;
}

// ------------------------------------------------- GEMM: B resident in registers
// Grid-stride (GB=1024, ~3 chunks/block) amortizes the 64KB/block B preload.
template <bool RELU, bool HASB>
__global__ __launch_bounds__(256) void gemm_breg(
    const float* __restrict__ in,
    const unsigned short* __restrict__ Wh, const unsigned short* __restrict__ Wl,
    const float* __restrict__ bias, float* __restrict__ out) {
  const int t = threadIdx.x;
  const int w = t >> 6, l = t & 63;
  const int lr = l & 15, kg = l >> 4;

  short8 Bh[2][4], Bl[2][4];
#pragma unroll
  for (int ct = 0; ct < 2; ++ct)
#pragma unroll
    for (int ks = 0; ks < 4; ++ks) {
      const size_t bo = (size_t)((w * 2 + ct) * 16 + lr) * DD + ks * 32 + kg * 8;
      Bh[ct][ks] = *(const short8*)(Wh + bo);
      Bl[ct][ks] = *(const short8*)(Wl + bo);
    }
  float bv0 = 0.f, bv1 = 0.f;
  if (HASB) {
    bv0 = bias[(w * 2 + 0) * 16 + lr];
    bv1 = bias[(w * 2 + 1) * 16 + lr];
  }

  for (int c = blockIdx.x; c < NN / 16; c += gridDim.x) {
    const float* ap = in + ((size_t)c * 16 + lr) * DD + kg * 8;
    float va[4][8];
#pragma unroll
    for (int ks = 0; ks < 4; ++ks) {
      *(float4*)&va[ks][0] = *(const float4*)(ap + ks * 32);
      *(float4*)&va[ks][4] = *(const float4*)(ap + ks * 32 + 4);
    }
    short8 ah[4], al[4];
#pragma unroll
    for (int ks = 0; ks < 4; ++ks)
#pragma unroll
      for (int j = 0; j < 8; ++j) {
        unsigned short h = f2bf_rne(va[ks][j]);
        ah[ks][j] = (short)h;
        al[ks][j] = (short)f2bf_rne(va[ks][j] - bf2f(h));
      }
    f32x4 acc[2];
    acc[0] = (f32x4){0.f, 0.f, 0.f, 0.f};
    acc[1] = (f32x4){0.f, 0.f, 0.f, 0.f};
#pragma unroll
    for (int ks = 0; ks < 4; ++ks) {
#pragma unroll
      for (int ct = 0; ct < 2; ++ct) {
        acc[ct] = __builtin_amdgcn_mfma_f32_16x16x32_bf16(ah[ks], Bh[ct][ks], acc[ct], 0, 0, 0);
        acc[ct] = __builtin_amdgcn_mfma_f32_16x16x32_bf16(ah[ks], Bl[ct][ks], acc[ct], 0, 0, 0);
        acc[ct] = __builtin_amdgcn_mfma_f32_16x16x32_bf16(al[ks], Bh[ct][ks], acc[ct], 0, 0, 0);
      }
    }
    // C layout: col = lane&15, row = (lane>>4)*4 + q
#pragma unroll
    for (int ct = 0; ct < 2; ++ct) {
      const float bb = ct ? bv1 : bv0;
      const int col = (w * 2 + ct) * 16 + lr;
#pragma unroll
      for (int q4 = 0; q4 < 4; ++q4) {
        float v = acc[ct][q4] + bb;
        if (RELU) v = fmaxf(v, 0.f);
        out[((size_t)c * 16 + kg * 4 + q4) * DD + col] = v;
      }
    }
  }
}

// ------------------------------------------------- fused predictor GEMMs
// P1 = xf@Wp1[:128] (in-place over xf), P2 = xf@Wp1[128:] + bp1.
// BOTH weight matrices' B-fragments live in registers; ONE pass over xf.
// Barrier per chunk: all 4 waves read the same 16 A-rows before P1 overwrite.
__global__ __launch_bounds__(256) void gemm_pred2(
    const float* __restrict__ in,
    const unsigned short* __restrict__ W1h, const unsigned short* __restrict__ W1l,
    const unsigned short* __restrict__ W2h, const unsigned short* __restrict__ W2l,
    const float* __restrict__ bp1,
    float* __restrict__ P1, float* __restrict__ P2) {
  const int t = threadIdx.x;
  const int w = t >> 6, l = t & 63;
  const int lr = l & 15, kg = l >> 4;

  short8 B1h[2][4], B1l[2][4], B2h[2][4], B2l[2][4];
#pragma unroll
  for (int ct = 0; ct < 2; ++ct)
#pragma unroll
    for (int ks = 0; ks < 4; ++ks) {
      const size_t bo = (size_t)((w * 2 + ct) * 16 + lr) * DD + ks * 32 + kg * 8;
      B1h[ct][ks] = *(const short8*)(W1h + bo);
      B1l[ct][ks] = *(const short8*)(W1l + bo);
      B2h[ct][ks] = *(const short8*)(W2h + bo);
      B2l[ct][ks] = *(const short8*)(W2l + bo);
    }
  float bv0 = bp1[(w * 2 + 0) * 16 + lr];
  float bv1 = bp1[(w * 2 + 1) * 16 + lr];

  for (int c = blockIdx.x; c < NN / 16; c += gridDim.x) {
    const float* ap = in + ((size_t)c * 16 + lr) * DD + kg * 8;
    float va[4][8];
#pragma unroll
    for (int ks = 0; ks < 4; ++ks) {
      *(float4*)&va[ks][0] = *(const float4*)(ap + ks * 32);
      *(float4*)&va[ks][4] = *(const float4*)(ap + ks * 32 + 4);
    }
    short8 ah[4], al[4];
#pragma unroll
    for (int ks = 0; ks < 4; ++ks)
#pragma unroll
      for (int j = 0; j < 8; ++j) {
        unsigned short h = f2bf_rne(va[ks][j]);
        ah[ks][j] = (short)h;
        al[ks][j] = (short)f2bf_rne(va[ks][j] - bf2f(h));
      }
    f32x4 acc1[2], acc2[2];
    acc1[0] = (f32x4){0.f, 0.f, 0.f, 0.f};
    acc1[1] = (f32x4){0.f, 0.f, 0.f, 0.f};
    acc2[0] = (f32x4){0.f, 0.f, 0.f, 0.f};
    acc2[1] = (f32x4){0.f, 0.f, 0.f, 0.f};
#pragma unroll
    for (int ks = 0; ks < 4; ++ks) {
#pragma unroll
      for (int ct = 0; ct < 2; ++ct) {
        acc1[ct] = __builtin_amdgcn_mfma_f32_16x16x32_bf16(ah[ks], B1h[ct][ks], acc1[ct], 0, 0, 0);
        acc1[ct] = __builtin_amdgcn_mfma_f32_16x16x32_bf16(ah[ks], B1l[ct][ks], acc1[ct], 0, 0, 0);
        acc1[ct] = __builtin_amdgcn_mfma_f32_16x16x32_bf16(al[ks], B1h[ct][ks], acc1[ct], 0, 0, 0);
        acc2[ct] = __builtin_amdgcn_mfma_f32_16x16x32_bf16(ah[ks], B2h[ct][ks], acc2[ct], 0, 0, 0);
        acc2[ct] = __builtin_amdgcn_mfma_f32_16x16x32_bf16(ah[ks], B2l[ct][ks], acc2[ct], 0, 0, 0);
        acc2[ct] = __builtin_amdgcn_mfma_f32_16x16x32_bf16(al[ks], B2h[ct][ks], acc2[ct], 0, 0, 0);
      }
    }
    __syncthreads();   // all waves done reading chunk's A rows (P1 aliases in)
#pragma unroll
    for (int ct = 0; ct < 2; ++ct) {
      const int col = (w * 2 + ct) * 16 + lr;
      const float bb = ct ? bv1 : bv0;
#pragma unroll
      for (int q4 = 0; q4 < 4; ++q4) {
        const size_t r = (size_t)c * 16 + kg * 4 + q4;
        P1[r * DD + col] = acc1[ct][q4];
        P2[r * DD + col] = acc2[ct][q4] + bb;
      }
    }
  }
}

// ------------------------------------------------- final edge pass (node-parallel)
// One node per 32-lane slot + 4-deep gather unroll.
__global__ __launch_bounds__(256) void edge_out(
    const float4* __restrict__ P1_4, const float4* __restrict__ P2_4,
    const int* __restrict__ offs, const int* __restrict__ srcs_s,
    const int* __restrict__ eid_s, const float4* __restrict__ Wp2_4,
    const float* __restrict__ bp2, float* __restrict__ out) {
  const int slot = threadIdx.x >> 5, lane = threadIdx.x & 31;
  const int n = blockIdx.x * 8 + slot;
  if (n >= NN) return;
  const float4 w = Wp2_4[lane];
  const float bb = bp2[0];
  const float4 p2 = P2_4[(size_t)n * 32 + lane];
  const int beg = offs[n], end = offs[n + 1];
  int i = beg;
  for (; i + 4 <= end; i += 4) {
    float v[4];
#pragma unroll
    for (int u = 0; u < 4; ++u) {
      const float4 q = P1_4[(size_t)srcs_s[i + u] * 32 + lane];
      v[u] = fmaxf(q.x + p2.x, 0.f) * w.x + fmaxf(q.y + p2.y, 0.f) * w.y
           + fmaxf(q.z + p2.z, 0.f) * w.z + fmaxf(q.w + p2.w, 0.f) * w.w;
    }
#pragma unroll
    for (int m = 16; m >= 1; m >>= 1) {
#pragma unroll
      for (int u = 0; u < 4; ++u) v[u] += __shfl_xor(v[u], m, 64);
    }
    if (lane == 0) {
#pragma unroll
      for (int u = 0; u < 4; ++u) out[eid_s[i + u]] = v[u] + bb;
    }
  }
  for (; i < end; ++i) {
    const float4 q = P1_4[(size_t)srcs_s[i] * 32 + lane];
    float v = fmaxf(q.x + p2.x, 0.f) * w.x + fmaxf(q.y + p2.y, 0.f) * w.y
            + fmaxf(q.z + p2.z, 0.f) * w.z + fmaxf(q.w + p2.w, 0.f) * w.w;
#pragma unroll
    for (int m = 16; m >= 1; m >>= 1) v += __shfl_xor(v, m, 64);
    if (lane == 0) out[eid_s[i]] = v + bb;
  }
}

// ---------------------------------------------------------------- launch
extern "C" void kernel_launch(void* const* d_in, const int* in_sizes, int n_in,
                              void* d_out, int out_size, void* d_ws, size_t ws_size,
                              hipStream_t stream) {
  const float* x_in = (const float*)d_in[0];
  const float* ea   = (const float*)d_in[1];
  const int*   ei   = (const int*)d_in[2];   // integer inputs arrive as int32
  const float* Wl1 = (const float*)d_in[3];
  const float* bl1 = (const float*)d_in[4];
  const float* Wl2 = (const float*)d_in[5];
  const float* bl2 = (const float*)d_in[6];
  const float* We  = (const float*)d_in[7];
  const float* be  = (const float*)d_in[8];
  const float* Wp1 = (const float*)d_in[9];
  const float* bp1 = (const float*)d_in[10];
  const float* Wp2 = (const float*)d_in[11];
  const float* bp2 = (const float*)d_in[12];
  const int* src = ei;
  const int* dst = ei + NE;

  // workspace layout (~62 MB)
  float* bufA   = (float*)d_ws;                    // NN*DD
  float* bufB   = bufA + (size_t)NN * DD;          // NN*DD
  int*   cnt    = (int*)(bufB + (size_t)NN * DD);  // NN
  int*   offs   = cnt + NN;                        // NN+1
  int*   cursor = offs + NN + 1;                   // NN
  int*   srcs_s = cursor + NN;                     // NE
  float* eas_s  = (float*)(srcs_s + NE);           // NE
  int*   eid_s  = (int*)(eas_s + NE);              // NE
  unsigned short* WTh = (unsigned short*)(eid_s + NE);  // 8*16384 bf16
  unsigned short* WTl = WTh + 8 * 16384;                // 8*16384 bf16

  // CSR build + weight prep (per-launch, deterministic)
  hipMemsetAsync(cnt, 0, NN * sizeof(int), stream);
  hist_dst<<<NE / 256, 256, 0, stream>>>(dst, cnt);
  scan_nodes<<<1, 1024, 0, stream>>>(cnt, offs, cursor);
  csr_fill<<<NE / 256, 256, 0, stream>>>(src, dst, ea, cursor, srcs_s, eas_s, eid_s);
  prep_w<<<(8 * 16384 + 255) / 256, 256, 0, stream>>>(Wl1, Wl2, Wp1, WTh, WTl);

  const int GB = 1024;            // gemm grid: ~3 chunks/block (amortize B preload)
  const int AB = (NN + 7) / 8;    // 6250 blocks: 1 node/slot (max TLP)
#define WH(g) (WTh + (size_t)(g) * 16384)
#define WL(g) (WTl + (size_t)(g) * 16384)

  // layer 0: x_in -> bufA -> bufB -> bufA
  aggregate<<<AB, 256, 0, stream>>>(
      x_in, offs, srcs_s, eas_s, (const float4*)We, (const float4*)be, bufA);
  gemm_breg<true, true><<<GB, 256, 0, stream>>>(bufA, WH(0), WL(0), bl1, bufB);
  gemm_breg<true, true><<<GB, 256, 0, stream>>>(bufB, WH(3), WL(3), bl2, bufA);
  // layer 1
  aggregate<<<AB, 256, 0, stream>>>(
      bufA, offs, srcs_s, eas_s, (const float4*)(We + DD), (const float4*)(be + DD), bufB);
  gemm_breg<true, true><<<GB, 256, 0, stream>>>(bufB, WH(1), WL(1), bl1 + DD, bufA);
  gemm_breg<true, true><<<GB, 256, 0, stream>>>(bufA, WH(4), WL(4), bl2 + DD, bufB);
  // layer 2
  aggregate<<<AB, 256, 0, stream>>>(
      bufB, offs, srcs_s, eas_s, (const float4*)(We + 2 * DD), (const float4*)(be + 2 * DD), bufA);
  gemm_breg<true, true><<<GB, 256, 0, stream>>>(bufA, WH(2), WL(2), bl1 + 2 * DD, bufB);
  gemm_breg<true, true><<<GB, 256, 0, stream>>>(bufB, WH(5), WL(5), bl2 + 2 * DD, bufA);
  // fused predictor: xf = bufA -> P1 (in place) + P2 (bufB), one pass
  gemm_pred2<<<GB, 256, 0, stream>>>(bufA, WH(6), WL(6), WH(7), WL(7), bp1, bufA, bufB);
  edge_out<<<AB, 256, 0, stream>>>(
      (const float4*)bufA, (const float4*)bufB, offs, srcs_s, eid_s,
      (const float4*)Wp2, bp2, (float*)d_out);
}

// Round 11
// 518.110 us; speedup vs baseline: 1.2917x; 1.0306x over previous
//
#include <hip/hip_runtime.h>

#define NN 50000
#define NE 800000
#define DD 128

typedef __attribute__((ext_vector_type(8))) short short8;
typedef __attribute__((ext_vector_type(4))) float f32x4;

__device__ inline unsigned short f2bf_rne(float f) {
  unsigned u = __float_as_uint(f);
  u += 0x7FFF + ((u >> 16) & 1);
  return (unsigned short)(u >> 16);
}
__device__ inline float bf2f(unsigned short h) {
  return __uint_as_float(((unsigned)h) << 16);
}

// ------------------------------------------------- CSR build: histogram
__global__ __launch_bounds__(256) void hist_dst(const int* __restrict__ dst,
                                                int* __restrict__ cnt) {
  int e = blockIdx.x * 256 + threadIdx.x;
  if (e < NE) atomicAdd(&cnt[dst[e]], 1);
}

// ------------------------------------------------- CSR build: scan (1 block)
__global__ __launch_bounds__(1024) void scan_nodes(const int* __restrict__ cnt,
                                                   int* __restrict__ offs,
                                                   int* __restrict__ cursor) {
  __shared__ int wsum[16];
  __shared__ int wpre[16];
  const int t = threadIdx.x;
  const int lane = t & 63, wv = t >> 6;
  int carry = 0;
  for (int base = 0; base < NN; base += 8192) {
    const int i0 = base + t * 8;
    int4 a = make_int4(0, 0, 0, 0), b = make_int4(0, 0, 0, 0);
    if (i0 + 8 <= NN) {
      a = *(const int4*)(cnt + i0);
      b = *(const int4*)(cnt + i0 + 4);
    } else if (i0 < NN) {
      int tmp[8];
      for (int j = 0; j < 8; ++j) tmp[j] = (i0 + j < NN) ? cnt[i0 + j] : 0;
      a = make_int4(tmp[0], tmp[1], tmp[2], tmp[3]);
      b = make_int4(tmp[4], tmp[5], tmp[6], tmp[7]);
    }
    const int own = a.x + a.y + a.z + a.w + b.x + b.y + b.z + b.w;
    int inc = own;
#pragma unroll
    for (int d = 1; d < 64; d <<= 1) {
      int v = __shfl_up(inc, d, 64);
      if (lane >= d) inc += v;
    }
    if (lane == 63) wsum[wv] = inc;
    __syncthreads();
    if (t < 16) {
      int v = wsum[t];
      int p = v;
#pragma unroll
      for (int d = 1; d < 16; d <<= 1) {
        int u = __shfl_up(p, d, 16);
        if (t >= d) p += u;
      }
      wpre[t] = p - v;
      if (t == 15) wsum[15] = p;
    }
    __syncthreads();
    int run = carry + wpre[wv] + inc - own;
    const int o0 = run,      o1 = o0 + a.x, o2 = o1 + a.y, o3 = o2 + a.z;
    const int o4 = o3 + a.w, o5 = o4 + b.x, o6 = o5 + b.y, o7 = o6 + b.z;
    if (i0 + 8 <= NN) {
      *(int4*)(offs + i0)       = make_int4(o0, o1, o2, o3);
      *(int4*)(offs + i0 + 4)   = make_int4(o4, o5, o6, o7);
      *(int4*)(cursor + i0)     = make_int4(o0, o1, o2, o3);
      *(int4*)(cursor + i0 + 4) = make_int4(o4, o5, o6, o7);
    } else if (i0 < NN) {
      const int o[8] = {o0, o1, o2, o3, o4, o5, o6, o7};
      for (int j = 0; j < 8; ++j)
        if (i0 + j < NN) { offs[i0 + j] = o[j]; cursor[i0 + j] = o[j]; }
    }
    carry += wsum[15];
    __syncthreads();
  }
  if (t == 0) offs[NN] = carry;
}

// ------------------------------------------------- CSR build: fill
__global__ __launch_bounds__(256) void csr_fill(
    const int* __restrict__ src, const int* __restrict__ dst,
    const float* __restrict__ ea, int* __restrict__ cursor,
    int* __restrict__ srcs_s, float* __restrict__ eas_s,
    int* __restrict__ eid_s) {
  int e = blockIdx.x * 256 + threadIdx.x;
  if (e >= NE) return;
  int pos = atomicAdd(&cursor[dst[e]], 1);
  srcs_s[pos] = src[e];
  eas_s[pos] = ea[e];
  eid_s[pos] = e;
}

// ------------------------------------------------- weight prep: transpose + split
__global__ __launch_bounds__(256) void prep_w(
    const float* __restrict__ Wl1, const float* __restrict__ Wl2,
    const float* __restrict__ Wp1,
    unsigned short* __restrict__ WTh, unsigned short* __restrict__ WTl) {
  int tid = blockIdx.x * 256 + threadIdx.x;  // 8 * 16384
  if (tid >= 8 * 16384) return;
  int g = tid >> 14, idx = tid & 16383;
  int n = idx >> 7, k = idx & 127;
  const float* s;
  if (g < 3) s = Wl1 + (size_t)g * 16384;
  else if (g < 6) s = Wl2 + (size_t)(g - 3) * 16384;
  else s = Wp1 + (size_t)(g - 6) * 16384;
  float v = s[k * 128 + n];
  unsigned short hi = f2bf_rne(v);
  WTh[tid] = hi;
  WTl[tid] = f2bf_rne(v - bf2f(hi));
}

// ------------------------------------------------- per-node aggregation
// One node per 32-lane slot (full-grid TLP) + 4-deep gather unroll (MLP).
__global__ __launch_bounds__(256) void aggregate(
    const float* __restrict__ x, const int* __restrict__ offs,
    const int* __restrict__ srcs_s, const float* __restrict__ eas_s,
    const float4* __restrict__ We4, const float4* __restrict__ be4,
    float* __restrict__ out) {
  const int slot = threadIdx.x >> 5, lane = threadIdx.x & 31;
  const int n = blockIdx.x * 8 + slot;
  if (n >= NN) return;
  const float4 wv = We4[lane], bv = be4[lane];
  float4 a0 = ((const float4*)(x + (size_t)n * DD))[lane];
  float4 a1 = make_float4(0.f, 0.f, 0.f, 0.f);
  float4 a2 = make_float4(0.f, 0.f, 0.f, 0.f);
  float4 a3 = make_float4(0.f, 0.f, 0.f, 0.f);
  const int beg = offs[n], end = offs[n + 1];
  int i = beg;
  for (; i + 4 <= end; i += 4) {
    const int s0 = srcs_s[i], s1 = srcs_s[i + 1];
    const int s2 = srcs_s[i + 2], s3 = srcs_s[i + 3];
    const float e0 = eas_s[i], e1 = eas_s[i + 1];
    const float e2 = eas_s[i + 2], e3 = eas_s[i + 3];
    const float4 x0 = ((const float4*)(x + (size_t)s0 * DD))[lane];
    const float4 x1 = ((const float4*)(x + (size_t)s1 * DD))[lane];
    const float4 x2 = ((const float4*)(x + (size_t)s2 * DD))[lane];
    const float4 x3 = ((const float4*)(x + (size_t)s3 * DD))[lane];
    a0.x += fmaxf(fmaf(e0, wv.x, bv.x) + x0.x, 0.f);
    a0.y += fmaxf(fmaf(e0, wv.y, bv.y) + x0.y, 0.f);
    a0.z += fmaxf(fmaf(e0, wv.z, bv.z) + x0.z, 0.f);
    a0.w += fmaxf(fmaf(e0, wv.w, bv.w) + x0.w, 0.f);
    a1.x += fmaxf(fmaf(e1, wv.x, bv.x) + x1.x, 0.f);
    a1.y += fmaxf(fmaf(e1, wv.y, bv.y) + x1.y, 0.f);
    a1.z += fmaxf(fmaf(e1, wv.z, bv.z) + x1.z, 0.f);
    a1.w += fmaxf(fmaf(e1, wv.w, bv.w) + x1.w, 0.f);
    a2.x += fmaxf(fmaf(e2, wv.x, bv.x) + x2.x, 0.f);
    a2.y += fmaxf(fmaf(e2, wv.y, bv.y) + x2.y, 0.f);
    a2.z += fmaxf(fmaf(e2, wv.z, bv.z) + x2.z, 0.f);
    a2.w += fmaxf(fmaf(e2, wv.w, bv.w) + x2.w, 0.f);
    a3.x += fmaxf(fmaf(e3, wv.x, bv.x) + x3.x, 0.f);
    a3.y += fmaxf(fmaf(e3, wv.y, bv.y) + x3.y, 0.f);
    a3.z += fmaxf(fmaf(e3, wv.z, bv.z) + x3.z, 0.f);
    a3.w += fmaxf(fmaf(e3, wv.w, bv.w) + x3.w, 0.f);
  }
  for (; i < end; ++i) {
    const int s0 = srcs_s[i];
    const float e0 = eas_s[i];
    const float4 x0 = ((const float4*)(x + (size_t)s0 * DD))[lane];
    a0.x += fmaxf(fmaf(e0, wv.x, bv.x) + x0.x, 0.f);
    a0.y += fmaxf(fmaf(e0, wv.y, bv.y) + x0.y, 0.f);
    a0.z += fmaxf(fmaf(e0, wv.z, bv.z) + x0.z, 0.f);
    a0.w += fmaxf(fmaf(e0, wv.w, bv.w) + x0.w, 0.f);
  }
  a0.x += a1.x + a2.x + a3.x;
  a0.y += a1.y + a2.y + a3.y;
  a0.z += a1.z + a2.z + a3.z;
  a0.w += a1.w + a2.w + a3.w;
  ((float4*)(out + (size_t)n * DD))[lane] = a0;
}

// ------------------------------------------------- GEMM: B resident in registers
// Grid-stride (GB=1024, ~3 chunks/block) amortizes the 64KB/block B preload.
template <bool RELU, bool HASB>
__global__ __launch_bounds__(256) void gemm_breg(
    const float* __restrict__ in,
    const unsigned short* __restrict__ Wh, const unsigned short* __restrict__ Wl,
    const float* __restrict__ bias, float* __restrict__ out) {
  const int t = threadIdx.x;
  const int w = t >> 6, l = t & 63;
  const int lr = l & 15, kg = l >> 4;

  short8 Bh[2][4], Bl[2][4];
#pragma unroll
  for (int ct = 0; ct < 2; ++ct)
#pragma unroll
    for (int ks = 0; ks < 4; ++ks) {
      const size_t bo = (size_t)((w * 2 + ct) * 16 + lr) * DD + ks * 32 + kg * 8;
      Bh[ct][ks] = *(const short8*)(Wh + bo);
      Bl[ct][ks] = *(const short8*)(Wl + bo);
    }
  float bv0 = 0.f, bv1 = 0.f;
  if (HASB) {
    bv0 = bias[(w * 2 + 0) * 16 + lr];
    bv1 = bias[(w * 2 + 1) * 16 + lr];
  }

  for (int c = blockIdx.x; c < NN / 16; c += gridDim.x) {
    const float* ap = in + ((size_t)c * 16 + lr) * DD + kg * 8;
    float va[4][8];
#pragma unroll
    for (int ks = 0; ks < 4; ++ks) {
      *(float4*)&va[ks][0] = *(const float4*)(ap + ks * 32);
      *(float4*)&va[ks][4] = *(const float4*)(ap + ks * 32 + 4);
    }
    short8 ah[4], al[4];
#pragma unroll
    for (int ks = 0; ks < 4; ++ks)
#pragma unroll
      for (int j = 0; j < 8; ++j) {
        unsigned short h = f2bf_rne(va[ks][j]);
        ah[ks][j] = (short)h;
        al[ks][j] = (short)f2bf_rne(va[ks][j] - bf2f(h));
      }
    f32x4 acc[2];
    acc[0] = (f32x4){0.f, 0.f, 0.f, 0.f};
    acc[1] = (f32x4){0.f, 0.f, 0.f, 0.f};
#pragma unroll
    for (int ks = 0; ks < 4; ++ks) {
#pragma unroll
      for (int ct = 0; ct < 2; ++ct) {
        acc[ct] = __builtin_amdgcn_mfma_f32_16x16x32_bf16(ah[ks], Bh[ct][ks], acc[ct], 0, 0, 0);
        acc[ct] = __builtin_amdgcn_mfma_f32_16x16x32_bf16(ah[ks], Bl[ct][ks], acc[ct], 0, 0, 0);
        acc[ct] = __builtin_amdgcn_mfma_f32_16x16x32_bf16(al[ks], Bh[ct][ks], acc[ct], 0, 0, 0);
      }
    }
    // C layout: col = lane&15, row = (lane>>4)*4 + q
#pragma unroll
    for (int ct = 0; ct < 2; ++ct) {
      const float bb = ct ? bv1 : bv0;
      const int col = (w * 2 + ct) * 16 + lr;
#pragma unroll
      for (int q4 = 0; q4 < 4; ++q4) {
        float v = acc[ct][q4] + bb;
        if (RELU) v = fmaxf(v, 0.f);
        out[((size_t)c * 16 + kg * 4 + q4) * DD + col] = v;
      }
    }
  }
}

// ------------------------------------------------- fused predictor GEMMs
// P2 = xf@Wp1[128:] + bp1 (f32, IN-PLACE over xf: chunk-local + barrier).
// P1 = xf@Wp1[:128] stored as bf16 (halves edge_out's gather bytes).
__global__ __launch_bounds__(256) void gemm_pred2(
    const float* __restrict__ in,
    const unsigned short* __restrict__ W1h, const unsigned short* __restrict__ W1l,
    const unsigned short* __restrict__ W2h, const unsigned short* __restrict__ W2l,
    const float* __restrict__ bp1,
    unsigned short* __restrict__ P1bf, float* __restrict__ P2) {
  const int t = threadIdx.x;
  const int w = t >> 6, l = t & 63;
  const int lr = l & 15, kg = l >> 4;

  short8 B1h[2][4], B1l[2][4], B2h[2][4], B2l[2][4];
#pragma unroll
  for (int ct = 0; ct < 2; ++ct)
#pragma unroll
    for (int ks = 0; ks < 4; ++ks) {
      const size_t bo = (size_t)((w * 2 + ct) * 16 + lr) * DD + ks * 32 + kg * 8;
      B1h[ct][ks] = *(const short8*)(W1h + bo);
      B1l[ct][ks] = *(const short8*)(W1l + bo);
      B2h[ct][ks] = *(const short8*)(W2h + bo);
      B2l[ct][ks] = *(const short8*)(W2l + bo);
    }
  float bv0 = bp1[(w * 2 + 0) * 16 + lr];
  float bv1 = bp1[(w * 2 + 1) * 16 + lr];

  for (int c = blockIdx.x; c < NN / 16; c += gridDim.x) {
    const float* ap = in + ((size_t)c * 16 + lr) * DD + kg * 8;
    float va[4][8];
#pragma unroll
    for (int ks = 0; ks < 4; ++ks) {
      *(float4*)&va[ks][0] = *(const float4*)(ap + ks * 32);
      *(float4*)&va[ks][4] = *(const float4*)(ap + ks * 32 + 4);
    }
    short8 ah[4], al[4];
#pragma unroll
    for (int ks = 0; ks < 4; ++ks)
#pragma unroll
      for (int j = 0; j < 8; ++j) {
        unsigned short h = f2bf_rne(va[ks][j]);
        ah[ks][j] = (short)h;
        al[ks][j] = (short)f2bf_rne(va[ks][j] - bf2f(h));
      }
    f32x4 acc1[2], acc2[2];
    acc1[0] = (f32x4){0.f, 0.f, 0.f, 0.f};
    acc1[1] = (f32x4){0.f, 0.f, 0.f, 0.f};
    acc2[0] = (f32x4){0.f, 0.f, 0.f, 0.f};
    acc2[1] = (f32x4){0.f, 0.f, 0.f, 0.f};
#pragma unroll
    for (int ks = 0; ks < 4; ++ks) {
#pragma unroll
      for (int ct = 0; ct < 2; ++ct) {
        acc1[ct] = __builtin_amdgcn_mfma_f32_16x16x32_bf16(ah[ks], B1h[ct][ks], acc1[ct], 0, 0, 0);
        acc1[ct] = __builtin_amdgcn_mfma_f32_16x16x32_bf16(ah[ks], B1l[ct][ks], acc1[ct], 0, 0, 0);
        acc1[ct] = __builtin_amdgcn_mfma_f32_16x16x32_bf16(al[ks], B1h[ct][ks], acc1[ct], 0, 0, 0);
        acc2[ct] = __builtin_amdgcn_mfma_f32_16x16x32_bf16(ah[ks], B2h[ct][ks], acc2[ct], 0, 0, 0);
        acc2[ct] = __builtin_amdgcn_mfma_f32_16x16x32_bf16(ah[ks], B2l[ct][ks], acc2[ct], 0, 0, 0);
        acc2[ct] = __builtin_amdgcn_mfma_f32_16x16x32_bf16(al[ks], B2h[ct][ks], acc2[ct], 0, 0, 0);
      }
    }
    __syncthreads();   // all waves done reading chunk's A rows (P2 aliases in)
#pragma unroll
    for (int ct = 0; ct < 2; ++ct) {
      const int col = (w * 2 + ct) * 16 + lr;
      const float bb = ct ? bv1 : bv0;
#pragma unroll
      for (int q4 = 0; q4 < 4; ++q4) {
        const size_t r = (size_t)c * 16 + kg * 4 + q4;
        P1bf[r * DD + col] = f2bf_rne(acc1[ct][q4]);
        P2[r * DD + col] = acc2[ct][q4] + bb;
      }
    }
  }
}

// ------------------------------------------------- final edge pass (node-parallel)
// One node per 32-lane slot + 4-deep gather unroll; P1 gathered as bf16 (256B/row).
__global__ __launch_bounds__(256) void edge_out(
    const unsigned short* __restrict__ P1bf, const float4* __restrict__ P2_4,
    const int* __restrict__ offs, const int* __restrict__ srcs_s,
    const int* __restrict__ eid_s, const float4* __restrict__ Wp2_4,
    const float* __restrict__ bp2, float* __restrict__ out) {
  const int slot = threadIdx.x >> 5, lane = threadIdx.x & 31;
  const int n = blockIdx.x * 8 + slot;
  if (n >= NN) return;
  const float4 w = Wp2_4[lane];
  const float bb = bp2[0];
  const float4 p2 = P2_4[(size_t)n * 32 + lane];
  const int beg = offs[n], end = offs[n + 1];
  int i = beg;
  for (; i + 4 <= end; i += 4) {
    float v[4];
#pragma unroll
    for (int u = 0; u < 4; ++u) {
      const uint2 qq = *(const uint2*)(P1bf + (size_t)srcs_s[i + u] * DD + lane * 4);
      const float q0 = __uint_as_float(qq.x << 16);
      const float q1 = __uint_as_float(qq.x & 0xffff0000u);
      const float q2 = __uint_as_float(qq.y << 16);
      const float q3 = __uint_as_float(qq.y & 0xffff0000u);
      v[u] = fmaxf(q0 + p2.x, 0.f) * w.x + fmaxf(q1 + p2.y, 0.f) * w.y
           + fmaxf(q2 + p2.z, 0.f) * w.z + fmaxf(q3 + p2.w, 0.f) * w.w;
    }
#pragma unroll
    for (int m = 16; m >= 1; m >>= 1) {
#pragma unroll
      for (int u = 0; u < 4; ++u) v[u] += __shfl_xor(v[u], m, 64);
    }
    if (lane == 0) {
#pragma unroll
      for (int u = 0; u < 4; ++u) out[eid_s[i + u]] = v[u] + bb;
    }
  }
  for (; i < end; ++i) {
    const uint2 qq = *(const uint2*)(P1bf + (size_t)srcs_s[i] * DD + lane * 4);
    const float q0 = __uint_as_float(qq.x << 16);
    const float q1 = __uint_as_float(qq.x & 0xffff0000u);
    const float q2 = __uint_as_float(qq.y << 16);
    const float q3 = __uint_as_float(qq.y & 0xffff0000u);
    float v = fmaxf(q0 + p2.x, 0.f) * w.x + fmaxf(q1 + p2.y, 0.f) * w.y
            + fmaxf(q2 + p2.z, 0.f) * w.z + fmaxf(q3 + p2.w, 0.f) * w.w;
#pragma unroll
    for (int m = 16; m >= 1; m >>= 1) v += __shfl_xor(v, m, 64);
    if (lane == 0) out[eid_s[i]] = v + bb;
  }
}

// ---------------------------------------------------------------- launch
extern "C" void kernel_launch(void* const* d_in, const int* in_sizes, int n_in,
                              void* d_out, int out_size, void* d_ws, size_t ws_size,
                              hipStream_t stream) {
  const float* x_in = (const float*)d_in[0];
  const float* ea   = (const float*)d_in[1];
  const int*   ei   = (const int*)d_in[2];   // integer inputs arrive as int32
  const float* Wl1 = (const float*)d_in[3];
  const float* bl1 = (const float*)d_in[4];
  const float* Wl2 = (const float*)d_in[5];
  const float* bl2 = (const float*)d_in[6];
  const float* We  = (const float*)d_in[7];
  const float* be  = (const float*)d_in[8];
  const float* Wp1 = (const float*)d_in[9];
  const float* bp1 = (const float*)d_in[10];
  const float* Wp2 = (const float*)d_in[11];
  const float* bp2 = (const float*)d_in[12];
  const int* src = ei;
  const int* dst = ei + NE;

  // workspace layout (~62 MB)
  float* bufA   = (float*)d_ws;                    // NN*DD
  float* bufB   = bufA + (size_t)NN * DD;          // NN*DD
  int*   cnt    = (int*)(bufB + (size_t)NN * DD);  // NN
  int*   offs   = cnt + NN;                        // NN+1
  int*   cursor = offs + NN + 1;                   // NN
  int*   srcs_s = cursor + NN;                     // NE
  float* eas_s  = (float*)(srcs_s + NE);           // NE
  int*   eid_s  = (int*)(eas_s + NE);              // NE
  unsigned short* WTh = (unsigned short*)(eid_s + NE);  // 8*16384 bf16
  unsigned short* WTl = WTh + 8 * 16384;                // 8*16384 bf16

  // CSR build + weight prep (per-launch, deterministic)
  hipMemsetAsync(cnt, 0, NN * sizeof(int), stream);
  hist_dst<<<NE / 256, 256, 0, stream>>>(dst, cnt);
  scan_nodes<<<1, 1024, 0, stream>>>(cnt, offs, cursor);
  csr_fill<<<NE / 256, 256, 0, stream>>>(src, dst, ea, cursor, srcs_s, eas_s, eid_s);
  prep_w<<<(8 * 16384 + 255) / 256, 256, 0, stream>>>(Wl1, Wl2, Wp1, WTh, WTl);

  const int GB = 1024;            // gemm grid: ~3 chunks/block (amortize B preload)
  const int AB = (NN + 7) / 8;    // 6250 blocks: 1 node/slot (max TLP)
#define WH(g) (WTh + (size_t)(g) * 16384)
#define WL(g) (WTl + (size_t)(g) * 16384)

  // layer 0: x_in -> bufA -> bufB -> bufA
  aggregate<<<AB, 256, 0, stream>>>(
      x_in, offs, srcs_s, eas_s, (const float4*)We, (const float4*)be, bufA);
  gemm_breg<true, true><<<GB, 256, 0, stream>>>(bufA, WH(0), WL(0), bl1, bufB);
  gemm_breg<true, true><<<GB, 256, 0, stream>>>(bufB, WH(3), WL(3), bl2, bufA);
  // layer 1
  aggregate<<<AB, 256, 0, stream>>>(
      bufA, offs, srcs_s, eas_s, (const float4*)(We + DD), (const float4*)(be + DD), bufB);
  gemm_breg<true, true><<<GB, 256, 0, stream>>>(bufB, WH(1), WL(1), bl1 + DD, bufA);
  gemm_breg<true, true><<<GB, 256, 0, stream>>>(bufA, WH(4), WL(4), bl2 + DD, bufB);
  // layer 2
  aggregate<<<AB, 256, 0, stream>>>(
      bufB, offs, srcs_s, eas_s, (const float4*)(We + 2 * DD), (const float4*)(be + 2 * DD), bufA);
  gemm_breg<true, true><<<GB, 256, 0, stream>>>(bufA, WH(2), WL(2), bl1 + 2 * DD, bufB);
  gemm_breg<true, true><<<GB, 256, 0, stream>>>(bufB, WH(5), WL(5), bl2 + 2 * DD, bufA);
  // fused predictor: xf = bufA.  P2 (f32) -> bufA in-place; P1 (bf16) -> bufB.
  gemm_pred2<<<GB, 256, 0, stream>>>(bufA, WH(6), WL(6), WH(7), WL(7), bp1,
                                     (unsigned short*)bufB, bufA);
  edge_out<<<AB, 256, 0, stream>>>(
      (const unsigned short*)bufB, (const float4*)bufA, offs, srcs_s, eid_s,
      (const float4*)Wp2, bp2, (float*)d_out);
}

// Round 12
// 483.926 us; speedup vs baseline: 1.3830x; 1.0706x over previous
//
#include <hip/hip_runtime.h>

#define NN 50000
#define NE 800000
#define DD 128

typedef __attribute__((ext_vector_type(8))) short short8;
typedef __attribute__((ext_vector_type(4))) float f32x4;

__device__ inline unsigned short f2bf_rne(float f) {
  unsigned u = __float_as_uint(f);
  u += 0x7FFF + ((u >> 16) & 1);
  return (unsigned short)(u >> 16);
}
__device__ inline float bf2f(unsigned short h) {
  return __uint_as_float(((unsigned)h) << 16);
}

// ------------------------------------------------- CSR build: histogram
__global__ __launch_bounds__(256) void hist_dst(const int* __restrict__ dst,
                                                int* __restrict__ cnt) {
  int e = blockIdx.x * 256 + threadIdx.x;
  if (e < NE) atomicAdd(&cnt[dst[e]], 1);
}

// ------------------------------------------------- CSR build: scan (1 block)
__global__ __launch_bounds__(1024) void scan_nodes(const int* __restrict__ cnt,
                                                   int* __restrict__ offs,
                                                   int* __restrict__ cursor) {
  __shared__ int wsum[16];
  __shared__ int wpre[16];
  const int t = threadIdx.x;
  const int lane = t & 63, wv = t >> 6;
  int carry = 0;
  for (int base = 0; base < NN; base += 8192) {
    const int i0 = base + t * 8;
    int4 a = make_int4(0, 0, 0, 0), b = make_int4(0, 0, 0, 0);
    if (i0 + 8 <= NN) {
      a = *(const int4*)(cnt + i0);
      b = *(const int4*)(cnt + i0 + 4);
    } else if (i0 < NN) {
      int tmp[8];
      for (int j = 0; j < 8; ++j) tmp[j] = (i0 + j < NN) ? cnt[i0 + j] : 0;
      a = make_int4(tmp[0], tmp[1], tmp[2], tmp[3]);
      b = make_int4(tmp[4], tmp[5], tmp[6], tmp[7]);
    }
    const int own = a.x + a.y + a.z + a.w + b.x + b.y + b.z + b.w;
    int inc = own;
#pragma unroll
    for (int d = 1; d < 64; d <<= 1) {
      int v = __shfl_up(inc, d, 64);
      if (lane >= d) inc += v;
    }
    if (lane == 63) wsum[wv] = inc;
    __syncthreads();
    if (t < 16) {
      int v = wsum[t];
      int p = v;
#pragma unroll
      for (int d = 1; d < 16; d <<= 1) {
        int u = __shfl_up(p, d, 16);
        if (t >= d) p += u;
      }
      wpre[t] = p - v;
      if (t == 15) wsum[15] = p;
    }
    __syncthreads();
    int run = carry + wpre[wv] + inc - own;
    const int o0 = run,      o1 = o0 + a.x, o2 = o1 + a.y, o3 = o2 + a.z;
    const int o4 = o3 + a.w, o5 = o4 + b.x, o6 = o5 + b.y, o7 = o6 + b.z;
    if (i0 + 8 <= NN) {
      *(int4*)(offs + i0)       = make_int4(o0, o1, o2, o3);
      *(int4*)(offs + i0 + 4)   = make_int4(o4, o5, o6, o7);
      *(int4*)(cursor + i0)     = make_int4(o0, o1, o2, o3);
      *(int4*)(cursor + i0 + 4) = make_int4(o4, o5, o6, o7);
    } else if (i0 < NN) {
      const int o[8] = {o0, o1, o2, o3, o4, o5, o6, o7};
      for (int j = 0; j < 8; ++j)
        if (i0 + j < NN) { offs[i0 + j] = o[j]; cursor[i0 + j] = o[j]; }
    }
    carry += wsum[15];
    __syncthreads();
  }
  if (t == 0) offs[NN] = carry;
}

// ------------------------------------------------- CSR build: fill (16B records)
// rec = {src, eid, ea_bits, 0}: ONE scattered dwordx4 per edge (vs 3 dwords).
__global__ __launch_bounds__(256) void csr_fill(
    const int* __restrict__ src, const int* __restrict__ dst,
    const float* __restrict__ ea, int* __restrict__ cursor,
    int4* __restrict__ recs) {
  int e = blockIdx.x * 256 + threadIdx.x;
  if (e >= NE) return;
  int pos = atomicAdd(&cursor[dst[e]], 1);
  recs[pos] = make_int4(src[e], e, __float_as_int(ea[e]), 0);
}

// ------------------------------------------------- weight prep: transpose + split
__global__ __launch_bounds__(256) void prep_w(
    const float* __restrict__ Wl1, const float* __restrict__ Wl2,
    const float* __restrict__ Wp1,
    unsigned short* __restrict__ WTh, unsigned short* __restrict__ WTl) {
  int tid = blockIdx.x * 256 + threadIdx.x;  // 8 * 16384
  if (tid >= 8 * 16384) return;
  int g = tid >> 14, idx = tid & 16383;
  int n = idx >> 7, k = idx & 127;
  const float* s;
  if (g < 3) s = Wl1 + (size_t)g * 16384;
  else if (g < 6) s = Wl2 + (size_t)(g - 3) * 16384;
  else s = Wp1 + (size_t)(g - 6) * 16384;
  float v = s[k * 128 + n];
  unsigned short hi = f2bf_rne(v);
  WTh[tid] = hi;
  WTl[tid] = f2bf_rne(v - bf2f(hi));
}

// ------------------------------------------------- f32 -> bf16 mirror of x_in
__global__ __launch_bounds__(256) void cvt_bf(const float2* __restrict__ in,
                                              unsigned* __restrict__ out, int n2) {
  int i = blockIdx.x * 256 + threadIdx.x;
  if (i < n2) {
    float2 v = in[i];
    out[i] = (unsigned)f2bf_rne(v.x) | ((unsigned)f2bf_rne(v.y) << 16);
  }
}

// ------------------------------------------------- per-node aggregation
// Self term from f32 x; neighbor rows gathered from bf16 mirror (256B/row).
__global__ __launch_bounds__(256) void aggregate(
    const float* __restrict__ x, const unsigned short* __restrict__ xbf,
    const int* __restrict__ offs, const int4* __restrict__ recs,
    const float4* __restrict__ We4, const float4* __restrict__ be4,
    float* __restrict__ out) {
  const int slot = threadIdx.x >> 5, lane = threadIdx.x & 31;
  const int n = blockIdx.x * 8 + slot;
  if (n >= NN) return;
  const float4 wv = We4[lane], bv = be4[lane];
  float4 a0 = ((const float4*)(x + (size_t)n * DD))[lane];
  float4 a1 = make_float4(0.f, 0.f, 0.f, 0.f);
  float4 a2 = make_float4(0.f, 0.f, 0.f, 0.f);
  float4 a3 = make_float4(0.f, 0.f, 0.f, 0.f);
  const int beg = offs[n], end = offs[n + 1];
  int i = beg;
#define GATH(acc, rec)                                                        \
  {                                                                           \
    const float ee = __int_as_float((rec).z);                                 \
    const uint2 qq = *(const uint2*)(xbf + (size_t)(rec).x * DD + lane * 4);  \
    const float g0 = __uint_as_float(qq.x << 16);                             \
    const float g1 = __uint_as_float(qq.x & 0xffff0000u);                     \
    const float g2 = __uint_as_float(qq.y << 16);                             \
    const float g3 = __uint_as_float(qq.y & 0xffff0000u);                     \
    acc.x += fmaxf(fmaf(ee, wv.x, bv.x) + g0, 0.f);                           \
    acc.y += fmaxf(fmaf(ee, wv.y, bv.y) + g1, 0.f);                           \
    acc.z += fmaxf(fmaf(ee, wv.z, bv.z) + g2, 0.f);                           \
    acc.w += fmaxf(fmaf(ee, wv.w, bv.w) + g3, 0.f);                           \
  }
  for (; i + 4 <= end; i += 4) {
    const int4 r0 = recs[i], r1 = recs[i + 1], r2 = recs[i + 2], r3 = recs[i + 3];
    GATH(a0, r0)
    GATH(a1, r1)
    GATH(a2, r2)
    GATH(a3, r3)
  }
  for (; i < end; ++i) {
    const int4 r0 = recs[i];
    GATH(a0, r0)
  }
#undef GATH
  a0.x += a1.x + a2.x + a3.x;
  a0.y += a1.y + a2.y + a3.y;
  a0.z += a1.z + a2.z + a3.z;
  a0.w += a1.w + a2.w + a3.w;
  ((float4*)(out + (size_t)n * DD))[lane] = a0;
}

// ------------------------------------------------- GEMM: B resident in registers
// DUALBF: epilogue additionally writes a bf16 mirror (feeds next aggregate).
template <bool RELU, bool HASB, bool DUALBF>
__global__ __launch_bounds__(256) void gemm_breg(
    const float* __restrict__ in,
    const unsigned short* __restrict__ Wh, const unsigned short* __restrict__ Wl,
    const float* __restrict__ bias, float* __restrict__ out,
    unsigned short* __restrict__ outbf) {
  const int t = threadIdx.x;
  const int w = t >> 6, l = t & 63;
  const int lr = l & 15, kg = l >> 4;

  short8 Bh[2][4], Bl[2][4];
#pragma unroll
  for (int ct = 0; ct < 2; ++ct)
#pragma unroll
    for (int ks = 0; ks < 4; ++ks) {
      const size_t bo = (size_t)((w * 2 + ct) * 16 + lr) * DD + ks * 32 + kg * 8;
      Bh[ct][ks] = *(const short8*)(Wh + bo);
      Bl[ct][ks] = *(const short8*)(Wl + bo);
    }
  float bv0 = 0.f, bv1 = 0.f;
  if (HASB) {
    bv0 = bias[(w * 2 + 0) * 16 + lr];
    bv1 = bias[(w * 2 + 1) * 16 + lr];
  }

  for (int c = blockIdx.x; c < NN / 16; c += gridDim.x) {
    const float* ap = in + ((size_t)c * 16 + lr) * DD + kg * 8;
    float va[4][8];
#pragma unroll
    for (int ks = 0; ks < 4; ++ks) {
      *(float4*)&va[ks][0] = *(const float4*)(ap + ks * 32);
      *(float4*)&va[ks][4] = *(const float4*)(ap + ks * 32 + 4);
    }
    short8 ah[4], al[4];
#pragma unroll
    for (int ks = 0; ks < 4; ++ks)
#pragma unroll
      for (int j = 0; j < 8; ++j) {
        unsigned short h = f2bf_rne(va[ks][j]);
        ah[ks][j] = (short)h;
        al[ks][j] = (short)f2bf_rne(va[ks][j] - bf2f(h));
      }
    f32x4 acc[2];
    acc[0] = (f32x4){0.f, 0.f, 0.f, 0.f};
    acc[1] = (f32x4){0.f, 0.f, 0.f, 0.f};
#pragma unroll
    for (int ks = 0; ks < 4; ++ks) {
#pragma unroll
      for (int ct = 0; ct < 2; ++ct) {
        acc[ct] = __builtin_amdgcn_mfma_f32_16x16x32_bf16(ah[ks], Bh[ct][ks], acc[ct], 0, 0, 0);
        acc[ct] = __builtin_amdgcn_mfma_f32_16x16x32_bf16(ah[ks], Bl[ct][ks], acc[ct], 0, 0, 0);
        acc[ct] = __builtin_amdgcn_mfma_f32_16x16x32_bf16(al[ks], Bh[ct][ks], acc[ct], 0, 0, 0);
      }
    }
    // C layout: col = lane&15, row = (lane>>4)*4 + q
#pragma unroll
    for (int ct = 0; ct < 2; ++ct) {
      const float bb = ct ? bv1 : bv0;
      const int col = (w * 2 + ct) * 16 + lr;
#pragma unroll
      for (int q4 = 0; q4 < 4; ++q4) {
        float v = acc[ct][q4] + bb;
        if (RELU) v = fmaxf(v, 0.f);
        const size_t r = (size_t)c * 16 + kg * 4 + q4;
        out[r * DD + col] = v;
        if (DUALBF) outbf[r * DD + col] = f2bf_rne(v);
      }
    }
  }
}

// ------------------------------------------------- fused predictor GEMMs
__global__ __launch_bounds__(256) void gemm_pred2(
    const float* __restrict__ in,
    const unsigned short* __restrict__ W1h, const unsigned short* __restrict__ W1l,
    const unsigned short* __restrict__ W2h, const unsigned short* __restrict__ W2l,
    const float* __restrict__ bp1,
    unsigned short* __restrict__ P1bf, float* __restrict__ P2) {
  const int t = threadIdx.x;
  const int w = t >> 6, l = t & 63;
  const int lr = l & 15, kg = l >> 4;

  short8 B1h[2][4], B1l[2][4], B2h[2][4], B2l[2][4];
#pragma unroll
  for (int ct = 0; ct < 2; ++ct)
#pragma unroll
    for (int ks = 0; ks < 4; ++ks) {
      const size_t bo = (size_t)((w * 2 + ct) * 16 + lr) * DD + ks * 32 + kg * 8;
      B1h[ct][ks] = *(const short8*)(W1h + bo);
      B1l[ct][ks] = *(const short8*)(W1l + bo);
      B2h[ct][ks] = *(const short8*)(W2h + bo);
      B2l[ct][ks] = *(const short8*)(W2l + bo);
    }
  float bv0 = bp1[(w * 2 + 0) * 16 + lr];
  float bv1 = bp1[(w * 2 + 1) * 16 + lr];

  for (int c = blockIdx.x; c < NN / 16; c += gridDim.x) {
    const float* ap = in + ((size_t)c * 16 + lr) * DD + kg * 8;
    float va[4][8];
#pragma unroll
    for (int ks = 0; ks < 4; ++ks) {
      *(float4*)&va[ks][0] = *(const float4*)(ap + ks * 32);
      *(float4*)&va[ks][4] = *(const float4*)(ap + ks * 32 + 4);
    }
    short8 ah[4], al[4];
#pragma unroll
    for (int ks = 0; ks < 4; ++ks)
#pragma unroll
      for (int j = 0; j < 8; ++j) {
        unsigned short h = f2bf_rne(va[ks][j]);
        ah[ks][j] = (short)h;
        al[ks][j] = (short)f2bf_rne(va[ks][j] - bf2f(h));
      }
    f32x4 acc1[2], acc2[2];
    acc1[0] = (f32x4){0.f, 0.f, 0.f, 0.f};
    acc1[1] = (f32x4){0.f, 0.f, 0.f, 0.f};
    acc2[0] = (f32x4){0.f, 0.f, 0.f, 0.f};
    acc2[1] = (f32x4){0.f, 0.f, 0.f, 0.f};
#pragma unroll
    for (int ks = 0; ks < 4; ++ks) {
#pragma unroll
      for (int ct = 0; ct < 2; ++ct) {
        acc1[ct] = __builtin_amdgcn_mfma_f32_16x16x32_bf16(ah[ks], B1h[ct][ks], acc1[ct], 0, 0, 0);
        acc1[ct] = __builtin_amdgcn_mfma_f32_16x16x32_bf16(ah[ks], B1l[ct][ks], acc1[ct], 0, 0, 0);
        acc1[ct] = __builtin_amdgcn_mfma_f32_16x16x32_bf16(al[ks], B1h[ct][ks], acc1[ct], 0, 0, 0);
        acc2[ct] = __builtin_amdgcn_mfma_f32_16x16x32_bf16(ah[ks], B2h[ct][ks], acc2[ct], 0, 0, 0);
        acc2[ct] = __builtin_amdgcn_mfma_f32_16x16x32_bf16(ah[ks], B2l[ct][ks], acc2[ct], 0, 0, 0);
        acc2[ct] = __builtin_amdgcn_mfma_f32_16x16x32_bf16(al[ks], B2h[ct][ks], acc2[ct], 0, 0, 0);
      }
    }
    __syncthreads();   // all waves done reading chunk's A rows (P2 aliases in)
#pragma unroll
    for (int ct = 0; ct < 2; ++ct) {
      const int col = (w * 2 + ct) * 16 + lr;
      const float bb = ct ? bv1 : bv0;
#pragma unroll
      for (int q4 = 0; q4 < 4; ++q4) {
        const size_t r = (size_t)c * 16 + kg * 4 + q4;
        P1bf[r * DD + col] = f2bf_rne(acc1[ct][q4]);
        P2[r * DD + col] = acc2[ct][q4] + bb;
      }
    }
  }
}

// ------------------------------------------------- final edge pass (node-parallel)
__global__ __launch_bounds__(256) void edge_out(
    const unsigned short* __restrict__ P1bf, const float4* __restrict__ P2_4,
    const int* __restrict__ offs, const int4* __restrict__ recs,
    const float4* __restrict__ Wp2_4,
    const float* __restrict__ bp2, float* __restrict__ out) {
  const int slot = threadIdx.x >> 5, lane = threadIdx.x & 31;
  const int n = blockIdx.x * 8 + slot;
  if (n >= NN) return;
  const float4 w = Wp2_4[lane];
  const float bb = bp2[0];
  const float4 p2 = P2_4[(size_t)n * 32 + lane];
  const int beg = offs[n], end = offs[n + 1];
  int i = beg;
  for (; i + 4 <= end; i += 4) {
    float v[4];
    int eid[4];
#pragma unroll
    for (int u = 0; u < 4; ++u) {
      const int4 rec = recs[i + u];
      eid[u] = rec.y;
      const uint2 qq = *(const uint2*)(P1bf + (size_t)rec.x * DD + lane * 4);
      const float q0 = __uint_as_float(qq.x << 16);
      const float q1 = __uint_as_float(qq.x & 0xffff0000u);
      const float q2 = __uint_as_float(qq.y << 16);
      const float q3 = __uint_as_float(qq.y & 0xffff0000u);
      v[u] = fmaxf(q0 + p2.x, 0.f) * w.x + fmaxf(q1 + p2.y, 0.f) * w.y
           + fmaxf(q2 + p2.z, 0.f) * w.z + fmaxf(q3 + p2.w, 0.f) * w.w;
    }
#pragma unroll
    for (int m = 16; m >= 1; m >>= 1) {
#pragma unroll
      for (int u = 0; u < 4; ++u) v[u] += __shfl_xor(v[u], m, 64);
    }
    if (lane == 0) {
#pragma unroll
      for (int u = 0; u < 4; ++u) out[eid[u]] = v[u] + bb;
    }
  }
  for (; i < end; ++i) {
    const int4 rec = recs[i];
    const uint2 qq = *(const uint2*)(P1bf + (size_t)rec.x * DD + lane * 4);
    const float q0 = __uint_as_float(qq.x << 16);
    const float q1 = __uint_as_float(qq.x & 0xffff0000u);
    const float q2 = __uint_as_float(qq.y << 16);
    const float q3 = __uint_as_float(qq.y & 0xffff0000u);
    float v = fmaxf(q0 + p2.x, 0.f) * w.x + fmaxf(q1 + p2.y, 0.f) * w.y
            + fmaxf(q2 + p2.z, 0.f) * w.z + fmaxf(q3 + p2.w, 0.f) * w.w;
#pragma unroll
    for (int m = 16; m >= 1; m >>= 1) v += __shfl_xor(v, m, 64);
    if (lane == 0) out[rec.y] = v + bb;
  }
}

// ---------------------------------------------------------------- launch
extern "C" void kernel_launch(void* const* d_in, const int* in_sizes, int n_in,
                              void* d_out, int out_size, void* d_ws, size_t ws_size,
                              hipStream_t stream) {
  const float* x_in = (const float*)d_in[0];
  const float* ea   = (const float*)d_in[1];
  const int*   ei   = (const int*)d_in[2];   // integer inputs arrive as int32
  const float* Wl1 = (const float*)d_in[3];
  const float* bl1 = (const float*)d_in[4];
  const float* Wl2 = (const float*)d_in[5];
  const float* bl2 = (const float*)d_in[6];
  const float* We  = (const float*)d_in[7];
  const float* be  = (const float*)d_in[8];
  const float* Wp1 = (const float*)d_in[9];
  const float* bp1 = (const float*)d_in[10];
  const float* Wp2 = (const float*)d_in[11];
  const float* bp2 = (const float*)d_in[12];
  const int* src = ei;
  const int* dst = ei + NE;

  // workspace layout (~78 MB)
  float* bufA   = (float*)d_ws;                    // NN*DD f32
  float* bufB   = bufA + (size_t)NN * DD;          // NN*DD f32
  int*   cnt    = (int*)(bufB + (size_t)NN * DD);  // NN
  int*   offs   = cnt + NN;                        // NN+1
  int*   cursor = offs + NN + 1;                   // NN
  int4*  recs   = (int4*)(((uintptr_t)(cursor + NN) + 15) & ~(uintptr_t)15); // NE
  unsigned short* WTh = (unsigned short*)(recs + NE);   // 8*16384 bf16
  unsigned short* WTl = WTh + 8 * 16384;                // 8*16384 bf16
  unsigned short* xbf = WTl + 8 * 16384;                // NN*DD bf16

  // CSR build + weight prep + x_in bf16 mirror (per-launch, deterministic)
  hipMemsetAsync(cnt, 0, NN * sizeof(int), stream);
  hist_dst<<<NE / 256, 256, 0, stream>>>(dst, cnt);
  scan_nodes<<<1, 1024, 0, stream>>>(cnt, offs, cursor);
  csr_fill<<<NE / 256, 256, 0, stream>>>(src, dst, ea, cursor, recs);
  prep_w<<<(8 * 16384 + 255) / 256, 256, 0, stream>>>(Wl1, Wl2, Wp1, WTh, WTl);
  cvt_bf<<<(NN * DD / 2 + 255) / 256, 256, 0, stream>>>(
      (const float2*)x_in, (unsigned*)xbf, NN * DD / 2);

  const int GB = 1024;            // gemm grid: ~3 chunks/block
  const int AB = (NN + 7) / 8;    // 6250 blocks: 1 node/slot (max TLP)
#define WH(g) (WTh + (size_t)(g) * 16384)
#define WL(g) (WTl + (size_t)(g) * 16384)

  // layer 0: agg(x_in,xbf)->bufA; g1 bufA->bufB; g2 bufB->bufA (+xbf=x1)
  aggregate<<<AB, 256, 0, stream>>>(
      x_in, xbf, offs, recs, (const float4*)We, (const float4*)be, bufA);
  gemm_breg<true, true, false><<<GB, 256, 0, stream>>>(bufA, WH(0), WL(0), bl1, bufB, nullptr);
  gemm_breg<true, true, true><<<GB, 256, 0, stream>>>(bufB, WH(3), WL(3), bl2, bufA, xbf);
  // layer 1: agg(bufA,xbf)->bufB; g1 bufB->bufA; g2 bufA->bufB (+xbf=x2)
  aggregate<<<AB, 256, 0, stream>>>(
      bufA, xbf, offs, recs, (const float4*)(We + DD), (const float4*)(be + DD), bufB);
  gemm_breg<true, true, false><<<GB, 256, 0, stream>>>(bufB, WH(1), WL(1), bl1 + DD, bufA, nullptr);
  gemm_breg<true, true, true><<<GB, 256, 0, stream>>>(bufA, WH(4), WL(4), bl2 + DD, bufB, xbf);
  // layer 2: agg(bufB,xbf)->bufA; g1 bufA->bufB; g2 bufB->bufA (f32 only)
  aggregate<<<AB, 256, 0, stream>>>(
      bufB, xbf, offs, recs, (const float4*)(We + 2 * DD), (const float4*)(be + 2 * DD), bufA);
  gemm_breg<true, true, false><<<GB, 256, 0, stream>>>(bufA, WH(2), WL(2), bl1 + 2 * DD, bufB, nullptr);
  gemm_breg<true, true, false><<<GB, 256, 0, stream>>>(bufB, WH(5), WL(5), bl2 + 2 * DD, bufA, nullptr);
  // fused predictor: xf = bufA.  P2 (f32) -> bufA in-place; P1 (bf16) -> bufB.
  gemm_pred2<<<GB, 256, 0, stream>>>(bufA, WH(6), WL(6), WH(7), WL(7), bp1,
                                     (unsigned short*)bufB, bufA);
  edge_out<<<AB, 256, 0, stream>>>(
      (const unsigned short*)bufB, (const float4*)bufA, offs, recs,
      (const float4*)Wp2, bp2, (float*)d_out);
}

// Round 13
// 455.473 us; speedup vs baseline: 1.4694x; 1.0625x over previous
//
#include <hip/hip_runtime.h>

#define NN 50000
#define NE 800000
#define DD 128

typedef __attribute__((ext_vector_type(8))) short short8;
typedef __attribute__((ext_vector_type(4))) float f32x4;

__device__ inline unsigned short f2bf_rne(float f) {
  unsigned u = __float_as_uint(f);
  u += 0x7FFF + ((u >> 16) & 1);
  return (unsigned short)(u >> 16);
}
__device__ inline float bf2f(unsigned short h) {
  return __uint_as_float(((unsigned)h) << 16);
}

// ------------------------------------------------- CSR build: histogram (4 edges/thread)
__global__ __launch_bounds__(256) void hist_dst(const int* __restrict__ dst,
                                                int* __restrict__ cnt) {
  int base = (blockIdx.x * 256 + threadIdx.x) * 4;
  if (base + 4 <= NE) {
    const int4 d = *(const int4*)(dst + base);
    atomicAdd(&cnt[d.x], 1);
    atomicAdd(&cnt[d.y], 1);
    atomicAdd(&cnt[d.z], 1);
    atomicAdd(&cnt[d.w], 1);
  } else {
    for (int e = base; e < NE; ++e) atomicAdd(&cnt[dst[e]], 1);
  }
}

// ------------------------------------------------- CSR build: scan (1 block)
__global__ __launch_bounds__(1024) void scan_nodes(const int* __restrict__ cnt,
                                                   int* __restrict__ offs,
                                                   int* __restrict__ cursor) {
  __shared__ int wsum[16];
  __shared__ int wpre[16];
  const int t = threadIdx.x;
  const int lane = t & 63, wv = t >> 6;
  int carry = 0;
  for (int base = 0; base < NN; base += 8192) {
    const int i0 = base + t * 8;
    int4 a = make_int4(0, 0, 0, 0), b = make_int4(0, 0, 0, 0);
    if (i0 + 8 <= NN) {
      a = *(const int4*)(cnt + i0);
      b = *(const int4*)(cnt + i0 + 4);
    } else if (i0 < NN) {
      int tmp[8];
      for (int j = 0; j < 8; ++j) tmp[j] = (i0 + j < NN) ? cnt[i0 + j] : 0;
      a = make_int4(tmp[0], tmp[1], tmp[2], tmp[3]);
      b = make_int4(tmp[4], tmp[5], tmp[6], tmp[7]);
    }
    const int own = a.x + a.y + a.z + a.w + b.x + b.y + b.z + b.w;
    int inc = own;
#pragma unroll
    for (int d = 1; d < 64; d <<= 1) {
      int v = __shfl_up(inc, d, 64);
      if (lane >= d) inc += v;
    }
    if (lane == 63) wsum[wv] = inc;
    __syncthreads();
    if (t < 16) {
      int v = wsum[t];
      int p = v;
#pragma unroll
      for (int d = 1; d < 16; d <<= 1) {
        int u = __shfl_up(p, d, 16);
        if (t >= d) p += u;
      }
      wpre[t] = p - v;
      if (t == 15) wsum[15] = p;
    }
    __syncthreads();
    int run = carry + wpre[wv] + inc - own;
    const int o0 = run,      o1 = o0 + a.x, o2 = o1 + a.y, o3 = o2 + a.z;
    const int o4 = o3 + a.w, o5 = o4 + b.x, o6 = o5 + b.y, o7 = o6 + b.z;
    if (i0 + 8 <= NN) {
      *(int4*)(offs + i0)       = make_int4(o0, o1, o2, o3);
      *(int4*)(offs + i0 + 4)   = make_int4(o4, o5, o6, o7);
      *(int4*)(cursor + i0)     = make_int4(o0, o1, o2, o3);
      *(int4*)(cursor + i0 + 4) = make_int4(o4, o5, o6, o7);
    } else if (i0 < NN) {
      const int o[8] = {o0, o1, o2, o3, o4, o5, o6, o7};
      for (int j = 0; j < 8; ++j)
        if (i0 + j < NN) { offs[i0 + j] = o[j]; cursor[i0 + j] = o[j]; }
    }
    carry += wsum[15];
    __syncthreads();
  }
  if (t == 0) offs[NN] = carry;
}

// ------------------------------------------------- CSR build: fill (4 edges/thread, 16B recs)
__global__ __launch_bounds__(256) void csr_fill(
    const int* __restrict__ src, const int* __restrict__ dst,
    const float* __restrict__ ea, int* __restrict__ cursor,
    int4* __restrict__ recs) {
  int base = (blockIdx.x * 256 + threadIdx.x) * 4;
  if (base + 4 <= NE) {
    const int4 d = *(const int4*)(dst + base);
    const int4 s = *(const int4*)(src + base);
    const float4 a = *(const float4*)(ea + base);
    int p0 = atomicAdd(&cursor[d.x], 1);
    int p1 = atomicAdd(&cursor[d.y], 1);
    int p2 = atomicAdd(&cursor[d.z], 1);
    int p3 = atomicAdd(&cursor[d.w], 1);
    recs[p0] = make_int4(s.x, base + 0, __float_as_int(a.x), 0);
    recs[p1] = make_int4(s.y, base + 1, __float_as_int(a.y), 0);
    recs[p2] = make_int4(s.z, base + 2, __float_as_int(a.z), 0);
    recs[p3] = make_int4(s.w, base + 3, __float_as_int(a.w), 0);
  } else {
    for (int e = base; e < NE; ++e) {
      int pos = atomicAdd(&cursor[dst[e]], 1);
      recs[pos] = make_int4(src[e], e, __float_as_int(ea[e]), 0);
    }
  }
}

// ------------------------------------------------- weight prep: transpose + split
__global__ __launch_bounds__(256) void prep_w(
    const float* __restrict__ Wl1, const float* __restrict__ Wl2,
    const float* __restrict__ Wp1,
    unsigned short* __restrict__ WTh, unsigned short* __restrict__ WTl) {
  int tid = blockIdx.x * 256 + threadIdx.x;  // 8 * 16384
  if (tid >= 8 * 16384) return;
  int g = tid >> 14, idx = tid & 16383;
  int n = idx >> 7, k = idx & 127;
  const float* s;
  if (g < 3) s = Wl1 + (size_t)g * 16384;
  else if (g < 6) s = Wl2 + (size_t)(g - 3) * 16384;
  else s = Wp1 + (size_t)(g - 6) * 16384;
  float v = s[k * 128 + n];
  unsigned short hi = f2bf_rne(v);
  WTh[tid] = hi;
  WTl[tid] = f2bf_rne(v - bf2f(hi));
}

// ------------------------------------------------- f32 -> bf16 mirror of x_in
__global__ __launch_bounds__(256) void cvt_bf(const float2* __restrict__ in,
                                              unsigned* __restrict__ out, int n2) {
  int i = blockIdx.x * 256 + threadIdx.x;
  if (i < n2) {
    float2 v = in[i];
    out[i] = (unsigned)f2bf_rne(v.x) | ((unsigned)f2bf_rne(v.y) << 16);
  }
}

// ------------------------------------------------- per-node aggregation
__global__ __launch_bounds__(256) void aggregate(
    const float* __restrict__ x, const unsigned short* __restrict__ xbf,
    const int* __restrict__ offs, const int4* __restrict__ recs,
    const float4* __restrict__ We4, const float4* __restrict__ be4,
    float* __restrict__ out) {
  const int slot = threadIdx.x >> 5, lane = threadIdx.x & 31;
  const int n = blockIdx.x * 8 + slot;
  if (n >= NN) return;
  const float4 wv = We4[lane], bv = be4[lane];
  float4 a0 = ((const float4*)(x + (size_t)n * DD))[lane];
  float4 a1 = make_float4(0.f, 0.f, 0.f, 0.f);
  float4 a2 = make_float4(0.f, 0.f, 0.f, 0.f);
  float4 a3 = make_float4(0.f, 0.f, 0.f, 0.f);
  const int beg = offs[n], end = offs[n + 1];
  int i = beg;
#define GATH(acc, rec)                                                        \
  {                                                                           \
    const float ee = __int_as_float((rec).z);                                 \
    const uint2 qq = *(const uint2*)(xbf + (size_t)(rec).x * DD + lane * 4);  \
    const float g0 = __uint_as_float(qq.x << 16);                             \
    const float g1 = __uint_as_float(qq.x & 0xffff0000u);                     \
    const float g2 = __uint_as_float(qq.y << 16);                             \
    const float g3 = __uint_as_float(qq.y & 0xffff0000u);                     \
    acc.x += fmaxf(fmaf(ee, wv.x, bv.x) + g0, 0.f);                           \
    acc.y += fmaxf(fmaf(ee, wv.y, bv.y) + g1, 0.f);                           \
    acc.z += fmaxf(fmaf(ee, wv.z, bv.z) + g2, 0.f);                           \
    acc.w += fmaxf(fmaf(ee, wv.w, bv.w) + g3, 0.f);                           \
  }
  for (; i + 4 <= end; i += 4) {
    const int4 r0 = recs[i], r1 = recs[i + 1], r2 = recs[i + 2], r3 = recs[i + 3];
    GATH(a0, r0)
    GATH(a1, r1)
    GATH(a2, r2)
    GATH(a3, r3)
  }
  for (; i < end; ++i) {
    const int4 r0 = recs[i];
    GATH(a0, r0)
  }
#undef GATH
  a0.x += a1.x + a2.x + a3.x;
  a0.y += a1.y + a2.y + a3.y;
  a0.z += a1.z + a2.z + a3.z;
  a0.w += a1.w + a2.w + a3.w;
  ((float4*)(out + (size_t)n * DD))[lane] = a0;
}

// ------------------------------------------------- fused layer MLP (B1+B2 in regs)
// out = relu(relu(in@W1+b1)@W2+b2); h passes through LDS [16][132] f32 (lossless).
// 2 barriers/chunk. DUALBF: also write bf16 mirror of out.
template <bool DUALBF>
__global__ __launch_bounds__(256) void fused_mlp(
    const float* __restrict__ in,
    const unsigned short* __restrict__ W1h, const unsigned short* __restrict__ W1l,
    const unsigned short* __restrict__ W2h, const unsigned short* __restrict__ W2l,
    const float* __restrict__ b1, const float* __restrict__ b2,
    float* __restrict__ out, unsigned short* __restrict__ outbf) {
  __shared__ float hl[16][132];
  const int t = threadIdx.x;
  const int w = t >> 6, l = t & 63;
  const int lr = l & 15, kg = l >> 4;

  short8 B1h_[2][4], B1l_[2][4], B2h_[2][4], B2l_[2][4];
#pragma unroll
  for (int ct = 0; ct < 2; ++ct)
#pragma unroll
    for (int ks = 0; ks < 4; ++ks) {
      const size_t bo = (size_t)((w * 2 + ct) * 16 + lr) * DD + ks * 32 + kg * 8;
      B1h_[ct][ks] = *(const short8*)(W1h + bo);
      B1l_[ct][ks] = *(const short8*)(W1l + bo);
      B2h_[ct][ks] = *(const short8*)(W2h + bo);
      B2l_[ct][ks] = *(const short8*)(W2l + bo);
    }
  const float b1v0 = b1[(w * 2 + 0) * 16 + lr];
  const float b1v1 = b1[(w * 2 + 1) * 16 + lr];
  const float b2v0 = b2[(w * 2 + 0) * 16 + lr];
  const float b2v1 = b2[(w * 2 + 1) * 16 + lr];

  for (int c = blockIdx.x; c < NN / 16; c += gridDim.x) {
    f32x4 acc[2];
    // ---- GEMM1: A from global f32
    {
      const float* ap = in + ((size_t)c * 16 + lr) * DD + kg * 8;
      float va[4][8];
#pragma unroll
      for (int ks = 0; ks < 4; ++ks) {
        *(float4*)&va[ks][0] = *(const float4*)(ap + ks * 32);
        *(float4*)&va[ks][4] = *(const float4*)(ap + ks * 32 + 4);
      }
      short8 ah[4], al[4];
#pragma unroll
      for (int ks = 0; ks < 4; ++ks)
#pragma unroll
        for (int j = 0; j < 8; ++j) {
          unsigned short h = f2bf_rne(va[ks][j]);
          ah[ks][j] = (short)h;
          al[ks][j] = (short)f2bf_rne(va[ks][j] - bf2f(h));
        }
      acc[0] = (f32x4){0.f, 0.f, 0.f, 0.f};
      acc[1] = (f32x4){0.f, 0.f, 0.f, 0.f};
#pragma unroll
      for (int ks = 0; ks < 4; ++ks)
#pragma unroll
        for (int ct = 0; ct < 2; ++ct) {
          acc[ct] = __builtin_amdgcn_mfma_f32_16x16x32_bf16(ah[ks], B1h_[ct][ks], acc[ct], 0, 0, 0);
          acc[ct] = __builtin_amdgcn_mfma_f32_16x16x32_bf16(ah[ks], B1l_[ct][ks], acc[ct], 0, 0, 0);
          acc[ct] = __builtin_amdgcn_mfma_f32_16x16x32_bf16(al[ks], B1h_[ct][ks], acc[ct], 0, 0, 0);
        }
    }
    // ---- h -> LDS (C layout: row = kg*4+q, col = tile*16+lr)
    __syncthreads();   // previous chunk's LDS readers done
#pragma unroll
    for (int ct = 0; ct < 2; ++ct) {
      const float bb = ct ? b1v1 : b1v0;
      const int col = (w * 2 + ct) * 16 + lr;
#pragma unroll
      for (int q = 0; q < 4; ++q)
        hl[kg * 4 + q][col] = fmaxf(acc[ct][q] + bb, 0.f);
    }
    __syncthreads();
    // ---- GEMM2: A from LDS
    {
      float va[4][8];
#pragma unroll
      for (int ks = 0; ks < 4; ++ks) {
        *(float4*)&va[ks][0] = *(const float4*)&hl[lr][ks * 32 + kg * 8];
        *(float4*)&va[ks][4] = *(const float4*)&hl[lr][ks * 32 + kg * 8 + 4];
      }
      short8 ah[4], al[4];
#pragma unroll
      for (int ks = 0; ks < 4; ++ks)
#pragma unroll
        for (int j = 0; j < 8; ++j) {
          unsigned short h = f2bf_rne(va[ks][j]);
          ah[ks][j] = (short)h;
          al[ks][j] = (short)f2bf_rne(va[ks][j] - bf2f(h));
        }
      acc[0] = (f32x4){0.f, 0.f, 0.f, 0.f};
      acc[1] = (f32x4){0.f, 0.f, 0.f, 0.f};
#pragma unroll
      for (int ks = 0; ks < 4; ++ks)
#pragma unroll
        for (int ct = 0; ct < 2; ++ct) {
          acc[ct] = __builtin_amdgcn_mfma_f32_16x16x32_bf16(ah[ks], B2h_[ct][ks], acc[ct], 0, 0, 0);
          acc[ct] = __builtin_amdgcn_mfma_f32_16x16x32_bf16(ah[ks], B2l_[ct][ks], acc[ct], 0, 0, 0);
          acc[ct] = __builtin_amdgcn_mfma_f32_16x16x32_bf16(al[ks], B2h_[ct][ks], acc[ct], 0, 0, 0);
        }
    }
    // ---- epilogue
#pragma unroll
    for (int ct = 0; ct < 2; ++ct) {
      const float bb = ct ? b2v1 : b2v0;
      const int col = (w * 2 + ct) * 16 + lr;
#pragma unroll
      for (int q = 0; q < 4; ++q) {
        const float v = fmaxf(acc[ct][q] + bb, 0.f);
        const size_t r = (size_t)c * 16 + kg * 4 + q;
        out[r * DD + col] = v;
        if (DUALBF) outbf[r * DD + col] = f2bf_rne(v);
      }
    }
  }
}

// ------------------------------------------------- fused predictor GEMMs
__global__ __launch_bounds__(256) void gemm_pred2(
    const float* __restrict__ in,
    const unsigned short* __restrict__ W1h, const unsigned short* __restrict__ W1l,
    const unsigned short* __restrict__ W2h, const unsigned short* __restrict__ W2l,
    const float* __restrict__ bp1,
    unsigned short* __restrict__ P1bf, float* __restrict__ P2) {
  const int t = threadIdx.x;
  const int w = t >> 6, l = t & 63;
  const int lr = l & 15, kg = l >> 4;

  short8 B1h[2][4], B1l[2][4], B2h[2][4], B2l[2][4];
#pragma unroll
  for (int ct = 0; ct < 2; ++ct)
#pragma unroll
    for (int ks = 0; ks < 4; ++ks) {
      const size_t bo = (size_t)((w * 2 + ct) * 16 + lr) * DD + ks * 32 + kg * 8;
      B1h[ct][ks] = *(const short8*)(W1h + bo);
      B1l[ct][ks] = *(const short8*)(W1l + bo);
      B2h[ct][ks] = *(const short8*)(W2h + bo);
      B2l[ct][ks] = *(const short8*)(W2l + bo);
    }
  float bv0 = bp1[(w * 2 + 0) * 16 + lr];
  float bv1 = bp1[(w * 2 + 1) * 16 + lr];

  for (int c = blockIdx.x; c < NN / 16; c += gridDim.x) {
    const float* ap = in + ((size_t)c * 16 + lr) * DD + kg * 8;
    float va[4][8];
#pragma unroll
    for (int ks = 0; ks < 4; ++ks) {
      *(float4*)&va[ks][0] = *(const float4*)(ap + ks * 32);
      *(float4*)&va[ks][4] = *(const float4*)(ap + ks * 32 + 4);
    }
    short8 ah[4], al[4];
#pragma unroll
    for (int ks = 0; ks < 4; ++ks)
#pragma unroll
      for (int j = 0; j < 8; ++j) {
        unsigned short h = f2bf_rne(va[ks][j]);
        ah[ks][j] = (short)h;
        al[ks][j] = (short)f2bf_rne(va[ks][j] - bf2f(h));
      }
    f32x4 acc1[2], acc2[2];
    acc1[0] = (f32x4){0.f, 0.f, 0.f, 0.f};
    acc1[1] = (f32x4){0.f, 0.f, 0.f, 0.f};
    acc2[0] = (f32x4){0.f, 0.f, 0.f, 0.f};
    acc2[1] = (f32x4){0.f, 0.f, 0.f, 0.f};
#pragma unroll
    for (int ks = 0; ks < 4; ++ks) {
#pragma unroll
      for (int ct = 0; ct < 2; ++ct) {
        acc1[ct] = __builtin_amdgcn_mfma_f32_16x16x32_bf16(ah[ks], B1h[ct][ks], acc1[ct], 0, 0, 0);
        acc1[ct] = __builtin_amdgcn_mfma_f32_16x16x32_bf16(ah[ks], B1l[ct][ks], acc1[ct], 0, 0, 0);
        acc1[ct] = __builtin_amdgcn_mfma_f32_16x16x32_bf16(al[ks], B1h[ct][ks], acc1[ct], 0, 0, 0);
        acc2[ct] = __builtin_amdgcn_mfma_f32_16x16x32_bf16(ah[ks], B2h[ct][ks], acc2[ct], 0, 0, 0);
        acc2[ct] = __builtin_amdgcn_mfma_f32_16x16x32_bf16(ah[ks], B2l[ct][ks], acc2[ct], 0, 0, 0);
        acc2[ct] = __builtin_amdgcn_mfma_f32_16x16x32_bf16(al[ks], B2h[ct][ks], acc2[ct], 0, 0, 0);
      }
    }
    __syncthreads();   // all waves done reading chunk's A rows (P2 aliases in)
#pragma unroll
    for (int ct = 0; ct < 2; ++ct) {
      const int col = (w * 2 + ct) * 16 + lr;
      const float bb = ct ? bv1 : bv0;
#pragma unroll
      for (int q4 = 0; q4 < 4; ++q4) {
        const size_t r = (size_t)c * 16 + kg * 4 + q4;
        P1bf[r * DD + col] = f2bf_rne(acc1[ct][q4]);
        P2[r * DD + col] = acc2[ct][q4] + bb;
      }
    }
  }
}

// ------------------------------------------------- final edge pass (node-parallel)
__global__ __launch_bounds__(256) void edge_out(
    const unsigned short* __restrict__ P1bf, const float4* __restrict__ P2_4,
    const int* __restrict__ offs, const int4* __restrict__ recs,
    const float4* __restrict__ Wp2_4,
    const float* __restrict__ bp2, float* __restrict__ out) {
  const int slot = threadIdx.x >> 5, lane = threadIdx.x & 31;
  const int n = blockIdx.x * 8 + slot;
  if (n >= NN) return;
  const float4 w = Wp2_4[lane];
  const float bb = bp2[0];
  const float4 p2 = P2_4[(size_t)n * 32 + lane];
  const int beg = offs[n], end = offs[n + 1];
  int i = beg;
  for (; i + 4 <= end; i += 4) {
    float v[4];
    int eid[4];
#pragma unroll
    for (int u = 0; u < 4; ++u) {
      const int4 rec = recs[i + u];
      eid[u] = rec.y;
      const uint2 qq = *(const uint2*)(P1bf + (size_t)rec.x * DD + lane * 4);
      const float q0 = __uint_as_float(qq.x << 16);
      const float q1 = __uint_as_float(qq.x & 0xffff0000u);
      const float q2 = __uint_as_float(qq.y << 16);
      const float q3 = __uint_as_float(qq.y & 0xffff0000u);
      v[u] = fmaxf(q0 + p2.x, 0.f) * w.x + fmaxf(q1 + p2.y, 0.f) * w.y
           + fmaxf(q2 + p2.z, 0.f) * w.z + fmaxf(q3 + p2.w, 0.f) * w.w;
    }
#pragma unroll
    for (int m = 16; m >= 1; m >>= 1) {
#pragma unroll
      for (int u = 0; u < 4; ++u) v[u] += __shfl_xor(v[u], m, 64);
    }
    if (lane == 0) {
#pragma unroll
      for (int u = 0; u < 4; ++u) out[eid[u]] = v[u] + bb;
    }
  }
  for (; i < end; ++i) {
    const int4 rec = recs[i];
    const uint2 qq = *(const uint2*)(P1bf + (size_t)rec.x * DD + lane * 4);
    const float q0 = __uint_as_float(qq.x << 16);
    const float q1 = __uint_as_float(qq.x & 0xffff0000u);
    const float q2 = __uint_as_float(qq.y << 16);
    const float q3 = __uint_as_float(qq.y & 0xffff0000u);
    float v = fmaxf(q0 + p2.x, 0.f) * w.x + fmaxf(q1 + p2.y, 0.f) * w.y
            + fmaxf(q2 + p2.z, 0.f) * w.z + fmaxf(q3 + p2.w, 0.f) * w.w;
#pragma unroll
    for (int m = 16; m >= 1; m >>= 1) v += __shfl_xor(v, m, 64);
    if (lane == 0) out[rec.y] = v + bb;
  }
}

// ---------------------------------------------------------------- launch
extern "C" void kernel_launch(void* const* d_in, const int* in_sizes, int n_in,
                              void* d_out, int out_size, void* d_ws, size_t ws_size,
                              hipStream_t stream) {
  const float* x_in = (const float*)d_in[0];
  const float* ea   = (const float*)d_in[1];
  const int*   ei   = (const int*)d_in[2];   // integer inputs arrive as int32
  const float* Wl1 = (const float*)d_in[3];
  const float* bl1 = (const float*)d_in[4];
  const float* Wl2 = (const float*)d_in[5];
  const float* bl2 = (const float*)d_in[6];
  const float* We  = (const float*)d_in[7];
  const float* be  = (const float*)d_in[8];
  const float* Wp1 = (const float*)d_in[9];
  const float* bp1 = (const float*)d_in[10];
  const float* Wp2 = (const float*)d_in[11];
  const float* bp2 = (const float*)d_in[12];
  const int* src = ei;
  const int* dst = ei + NE;

  // workspace layout (~78 MB)
  float* bufA   = (float*)d_ws;                    // NN*DD f32
  float* bufB   = bufA + (size_t)NN * DD;          // NN*DD f32
  int*   cnt    = (int*)(bufB + (size_t)NN * DD);  // NN
  int*   offs   = cnt + NN;                        // NN+1
  int*   cursor = offs + NN + 1;                   // NN
  int4*  recs   = (int4*)(((uintptr_t)(cursor + NN) + 15) & ~(uintptr_t)15); // NE
  unsigned short* WTh = (unsigned short*)(recs + NE);   // 8*16384 bf16
  unsigned short* WTl = WTh + 8 * 16384;                // 8*16384 bf16
  unsigned short* xbf = WTl + 8 * 16384;                // NN*DD bf16

  // CSR build + weight prep + x_in bf16 mirror (per-launch, deterministic)
  hipMemsetAsync(cnt, 0, NN * sizeof(int), stream);
  hist_dst<<<(NE / 4 + 255) / 256, 256, 0, stream>>>(dst, cnt);
  scan_nodes<<<1, 1024, 0, stream>>>(cnt, offs, cursor);
  csr_fill<<<(NE / 4 + 255) / 256, 256, 0, stream>>>(src, dst, ea, cursor, recs);
  prep_w<<<(8 * 16384 + 255) / 256, 256, 0, stream>>>(Wl1, Wl2, Wp1, WTh, WTl);
  cvt_bf<<<(NN * DD / 2 + 255) / 256, 256, 0, stream>>>(
      (const float2*)x_in, (unsigned*)xbf, NN * DD / 2);

  const int GB = 1024;            // gemm grid: ~3 chunks/block
  const int AB = (NN + 7) / 8;    // 6250 blocks: 1 node/slot (max TLP)
#define WH(g) (WTh + (size_t)(g) * 16384)
#define WL(g) (WTl + (size_t)(g) * 16384)

  // L0: agg(x_in,xbf)->A; fused A->B (+xbf=x1)
  aggregate<<<AB, 256, 0, stream>>>(
      x_in, xbf, offs, recs, (const float4*)We, (const float4*)be, bufA);
  fused_mlp<true><<<GB, 256, 0, stream>>>(
      bufA, WH(0), WL(0), WH(3), WL(3), bl1, bl2, bufB, xbf);
  // L1: agg(B,xbf)->A; fused A->B (+xbf=x2)
  aggregate<<<AB, 256, 0, stream>>>(
      bufB, xbf, offs, recs, (const float4*)(We + DD), (const float4*)(be + DD), bufA);
  fused_mlp<true><<<GB, 256, 0, stream>>>(
      bufA, WH(1), WL(1), WH(4), WL(4), bl1 + DD, bl2 + DD, bufB, xbf);
  // L2: agg(B,xbf)->A; fused A->B (f32 only)
  aggregate<<<AB, 256, 0, stream>>>(
      bufB, xbf, offs, recs, (const float4*)(We + 2 * DD), (const float4*)(be + 2 * DD), bufA);
  fused_mlp<false><<<GB, 256, 0, stream>>>(
      bufA, WH(2), WL(2), WH(5), WL(5), bl1 + 2 * DD, bl2 + 2 * DD, bufB, nullptr);
  // predictor: xf = bufB.  P1 (bf16) -> bufA's storage; P2 (f32) -> bufB in-place.
  gemm_pred2<<<GB, 256, 0, stream>>>(bufB, WH(6), WL(6), WH(7), WL(7), bp1,
                                     (unsigned short*)bufA, bufB);
  edge_out<<<AB, 256, 0, stream>>>(
      (const unsigned short*)bufA, (const float4*)bufB, offs, recs,
      (const float4*)Wp2, bp2, (float*)d_out);
}

// Round 14
// 408.225 us; speedup vs baseline: 1.6394x; 1.1157x over previous
//
#include <hip/hip_runtime.h>

#define NN 50000
#define NE 800000
#define DD 128

typedef __attribute__((ext_vector_type(8))) short short8;
typedef __attribute__((ext_vector_type(4))) float f32x4;

__device__ inline unsigned short f2bf_rne(float f) {
  unsigned u = __float_as_uint(f);
  u += 0x7FFF + ((u >> 16) & 1);
  return (unsigned short)(u >> 16);
}
__device__ inline float bf2f(unsigned short h) {
  return __uint_as_float(((unsigned)h) << 16);
}

// ------------------------------------------------- CSR build: histogram + rank
// rank[e] = this edge's arrival index within its dst bucket (atomic return).
__global__ __launch_bounds__(256) void hist_rank(const int* __restrict__ dst,
                                                 int* __restrict__ cnt,
                                                 int* __restrict__ rank) {
  int e = blockIdx.x * 256 + threadIdx.x;
  if (e < NE) rank[e] = atomicAdd(&cnt[dst[e]], 1);
}

// ------------------------------------------------- CSR build: scan (1 block)
__global__ __launch_bounds__(1024) void scan_nodes(const int* __restrict__ cnt,
                                                   int* __restrict__ offs) {
  __shared__ int wsum[16];
  __shared__ int wpre[16];
  const int t = threadIdx.x;
  const int lane = t & 63, wv = t >> 6;
  int carry = 0;
  for (int base = 0; base < NN; base += 8192) {
    const int i0 = base + t * 8;
    int4 a = make_int4(0, 0, 0, 0), b = make_int4(0, 0, 0, 0);
    if (i0 + 8 <= NN) {
      a = *(const int4*)(cnt + i0);
      b = *(const int4*)(cnt + i0 + 4);
    } else if (i0 < NN) {
      int tmp[8];
      for (int j = 0; j < 8; ++j) tmp[j] = (i0 + j < NN) ? cnt[i0 + j] : 0;
      a = make_int4(tmp[0], tmp[1], tmp[2], tmp[3]);
      b = make_int4(tmp[4], tmp[5], tmp[6], tmp[7]);
    }
    const int own = a.x + a.y + a.z + a.w + b.x + b.y + b.z + b.w;
    int inc = own;
#pragma unroll
    for (int d = 1; d < 64; d <<= 1) {
      int v = __shfl_up(inc, d, 64);
      if (lane >= d) inc += v;
    }
    if (lane == 63) wsum[wv] = inc;
    __syncthreads();
    if (t < 16) {
      int v = wsum[t];
      int p = v;
#pragma unroll
      for (int d = 1; d < 16; d <<= 1) {
        int u = __shfl_up(p, d, 16);
        if (t >= d) p += u;
      }
      wpre[t] = p - v;
      if (t == 15) wsum[15] = p;
    }
    __syncthreads();
    int run = carry + wpre[wv] + inc - own;
    const int o0 = run,      o1 = o0 + a.x, o2 = o1 + a.y, o3 = o2 + a.z;
    const int o4 = o3 + a.w, o5 = o4 + b.x, o6 = o5 + b.y, o7 = o6 + b.z;
    if (i0 + 8 <= NN) {
      *(int4*)(offs + i0)     = make_int4(o0, o1, o2, o3);
      *(int4*)(offs + i0 + 4) = make_int4(o4, o5, o6, o7);
    } else if (i0 < NN) {
      const int o[8] = {o0, o1, o2, o3, o4, o5, o6, o7};
      for (int j = 0; j < 8; ++j)
        if (i0 + j < NN) offs[i0 + j] = o[j];
    }
    carry += wsum[15];
    __syncthreads();
  }
  if (t == 0) offs[NN] = carry;
}

// ------------------------------------------------- CSR build: fill (NO atomics)
// pos = offs[dst] + rank  (rank captured during histogram).
__global__ __launch_bounds__(256) void csr_fill(
    const int* __restrict__ src, const int* __restrict__ dst,
    const float* __restrict__ ea, const int* __restrict__ offs,
    const int* __restrict__ rank, int4* __restrict__ recs) {
  int e = blockIdx.x * 256 + threadIdx.x;
  if (e >= NE) return;
  int pos = offs[dst[e]] + rank[e];
  recs[pos] = make_int4(src[e], e, __float_as_int(ea[e]), 0);
}

// ------------------------------------------------- weight prep: transpose + split
__global__ __launch_bounds__(256) void prep_w(
    const float* __restrict__ Wl1, const float* __restrict__ Wl2,
    const float* __restrict__ Wp1,
    unsigned short* __restrict__ WTh, unsigned short* __restrict__ WTl) {
  int tid = blockIdx.x * 256 + threadIdx.x;  // 8 * 16384
  if (tid >= 8 * 16384) return;
  int g = tid >> 14, idx = tid & 16383;
  int n = idx >> 7, k = idx & 127;
  const float* s;
  if (g < 3) s = Wl1 + (size_t)g * 16384;
  else if (g < 6) s = Wl2 + (size_t)(g - 3) * 16384;
  else s = Wp1 + (size_t)(g - 6) * 16384;
  float v = s[k * 128 + n];
  unsigned short hi = f2bf_rne(v);
  WTh[tid] = hi;
  WTl[tid] = f2bf_rne(v - bf2f(hi));
}

// ------------------------------------------------- f32 -> bf16 mirror of x_in
__global__ __launch_bounds__(256) void cvt_bf(const float2* __restrict__ in,
                                              unsigned* __restrict__ out, int n2) {
  int i = blockIdx.x * 256 + threadIdx.x;
  if (i < n2) {
    float2 v = in[i];
    out[i] = (unsigned)f2bf_rne(v.x) | ((unsigned)f2bf_rne(v.y) << 16);
  }
}

// ------------------------------------------------- per-node aggregation
__global__ __launch_bounds__(256) void aggregate(
    const float* __restrict__ x, const unsigned short* __restrict__ xbf,
    const int* __restrict__ offs, const int4* __restrict__ recs,
    const float4* __restrict__ We4, const float4* __restrict__ be4,
    float* __restrict__ out) {
  const int slot = threadIdx.x >> 5, lane = threadIdx.x & 31;
  const int n = blockIdx.x * 8 + slot;
  if (n >= NN) return;
  const float4 wv = We4[lane], bv = be4[lane];
  float4 a0 = ((const float4*)(x + (size_t)n * DD))[lane];
  float4 a1 = make_float4(0.f, 0.f, 0.f, 0.f);
  float4 a2 = make_float4(0.f, 0.f, 0.f, 0.f);
  float4 a3 = make_float4(0.f, 0.f, 0.f, 0.f);
  const int beg = offs[n], end = offs[n + 1];
  int i = beg;
#define GATH(acc, rec)                                                        \
  {                                                                           \
    const float ee = __int_as_float((rec).z);                                 \
    const uint2 qq = *(const uint2*)(xbf + (size_t)(rec).x * DD + lane * 4);  \
    const float g0 = __uint_as_float(qq.x << 16);                             \
    const float g1 = __uint_as_float(qq.x & 0xffff0000u);                     \
    const float g2 = __uint_as_float(qq.y << 16);                             \
    const float g3 = __uint_as_float(qq.y & 0xffff0000u);                     \
    acc.x += fmaxf(fmaf(ee, wv.x, bv.x) + g0, 0.f);                           \
    acc.y += fmaxf(fmaf(ee, wv.y, bv.y) + g1, 0.f);                           \
    acc.z += fmaxf(fmaf(ee, wv.z, bv.z) + g2, 0.f);                           \
    acc.w += fmaxf(fmaf(ee, wv.w, bv.w) + g3, 0.f);                           \
  }
  for (; i + 4 <= end; i += 4) {
    const int4 r0 = recs[i], r1 = recs[i + 1], r2 = recs[i + 2], r3 = recs[i + 3];
    GATH(a0, r0)
    GATH(a1, r1)
    GATH(a2, r2)
    GATH(a3, r3)
  }
  for (; i < end; ++i) {
    const int4 r0 = recs[i];
    GATH(a0, r0)
  }
#undef GATH
  a0.x += a1.x + a2.x + a3.x;
  a0.y += a1.y + a2.y + a3.y;
  a0.z += a1.z + a2.z + a3.z;
  a0.w += a1.w + a2.w + a3.w;
  ((float4*)(out + (size_t)n * DD))[lane] = a0;
}

// ------------------------------------------------- fused layer MLP (B1+B2 in regs)
template <bool DUALBF>
__global__ __launch_bounds__(256) void fused_mlp(
    const float* __restrict__ in,
    const unsigned short* __restrict__ W1h, const unsigned short* __restrict__ W1l,
    const unsigned short* __restrict__ W2h, const unsigned short* __restrict__ W2l,
    const float* __restrict__ b1, const float* __restrict__ b2,
    float* __restrict__ out, unsigned short* __restrict__ outbf) {
  __shared__ float hl[16][132];
  const int t = threadIdx.x;
  const int w = t >> 6, l = t & 63;
  const int lr = l & 15, kg = l >> 4;

  short8 B1h_[2][4], B1l_[2][4], B2h_[2][4], B2l_[2][4];
#pragma unroll
  for (int ct = 0; ct < 2; ++ct)
#pragma unroll
    for (int ks = 0; ks < 4; ++ks) {
      const size_t bo = (size_t)((w * 2 + ct) * 16 + lr) * DD + ks * 32 + kg * 8;
      B1h_[ct][ks] = *(const short8*)(W1h + bo);
      B1l_[ct][ks] = *(const short8*)(W1l + bo);
      B2h_[ct][ks] = *(const short8*)(W2h + bo);
      B2l_[ct][ks] = *(const short8*)(W2l + bo);
    }
  const float b1v0 = b1[(w * 2 + 0) * 16 + lr];
  const float b1v1 = b1[(w * 2 + 1) * 16 + lr];
  const float b2v0 = b2[(w * 2 + 0) * 16 + lr];
  const float b2v1 = b2[(w * 2 + 1) * 16 + lr];

  for (int c = blockIdx.x; c < NN / 16; c += gridDim.x) {
    f32x4 acc[2];
    // ---- GEMM1: A from global f32
    {
      const float* ap = in + ((size_t)c * 16 + lr) * DD + kg * 8;
      float va[4][8];
#pragma unroll
      for (int ks = 0; ks < 4; ++ks) {
        *(float4*)&va[ks][0] = *(const float4*)(ap + ks * 32);
        *(float4*)&va[ks][4] = *(const float4*)(ap + ks * 32 + 4);
      }
      short8 ah[4], al[4];
#pragma unroll
      for (int ks = 0; ks < 4; ++ks)
#pragma unroll
        for (int j = 0; j < 8; ++j) {
          unsigned short h = f2bf_rne(va[ks][j]);
          ah[ks][j] = (short)h;
          al[ks][j] = (short)f2bf_rne(va[ks][j] - bf2f(h));
        }
      acc[0] = (f32x4){0.f, 0.f, 0.f, 0.f};
      acc[1] = (f32x4){0.f, 0.f, 0.f, 0.f};
#pragma unroll
      for (int ks = 0; ks < 4; ++ks)
#pragma unroll
        for (int ct = 0; ct < 2; ++ct) {
          acc[ct] = __builtin_amdgcn_mfma_f32_16x16x32_bf16(ah[ks], B1h_[ct][ks], acc[ct], 0, 0, 0);
          acc[ct] = __builtin_amdgcn_mfma_f32_16x16x32_bf16(ah[ks], B1l_[ct][ks], acc[ct], 0, 0, 0);
          acc[ct] = __builtin_amdgcn_mfma_f32_16x16x32_bf16(al[ks], B1h_[ct][ks], acc[ct], 0, 0, 0);
        }
    }
    // ---- h -> LDS
    __syncthreads();
#pragma unroll
    for (int ct = 0; ct < 2; ++ct) {
      const float bb = ct ? b1v1 : b1v0;
      const int col = (w * 2 + ct) * 16 + lr;
#pragma unroll
      for (int q = 0; q < 4; ++q)
        hl[kg * 4 + q][col] = fmaxf(acc[ct][q] + bb, 0.f);
    }
    __syncthreads();
    // ---- GEMM2: A from LDS
    {
      float va[4][8];
#pragma unroll
      for (int ks = 0; ks < 4; ++ks) {
        *(float4*)&va[ks][0] = *(const float4*)&hl[lr][ks * 32 + kg * 8];
        *(float4*)&va[ks][4] = *(const float4*)&hl[lr][ks * 32 + kg * 8 + 4];
      }
      short8 ah[4], al[4];
#pragma unroll
      for (int ks = 0; ks < 4; ++ks)
#pragma unroll
        for (int j = 0; j < 8; ++j) {
          unsigned short h = f2bf_rne(va[ks][j]);
          ah[ks][j] = (short)h;
          al[ks][j] = (short)f2bf_rne(va[ks][j] - bf2f(h));
        }
      acc[0] = (f32x4){0.f, 0.f, 0.f, 0.f};
      acc[1] = (f32x4){0.f, 0.f, 0.f, 0.f};
#pragma unroll
      for (int ks = 0; ks < 4; ++ks)
#pragma unroll
        for (int ct = 0; ct < 2; ++ct) {
          acc[ct] = __builtin_amdgcn_mfma_f32_16x16x32_bf16(ah[ks], B2h_[ct][ks], acc[ct], 0, 0, 0);
          acc[ct] = __builtin_amdgcn_mfma_f32_16x16x32_bf16(ah[ks], B2l_[ct][ks], acc[ct], 0, 0, 0);
          acc[ct] = __builtin_amdgcn_mfma_f32_16x16x32_bf16(al[ks], B2h_[ct][ks], acc[ct], 0, 0, 0);
        }
    }
    // ---- epilogue
#pragma unroll
    for (int ct = 0; ct < 2; ++ct) {
      const float bb = ct ? b2v1 : b2v0;
      const int col = (w * 2 + ct) * 16 + lr;
#pragma unroll
      for (int q = 0; q < 4; ++q) {
        const float v = fmaxf(acc[ct][q] + bb, 0.f);
        const size_t r = (size_t)c * 16 + kg * 4 + q;
        out[r * DD + col] = v;
        if (DUALBF) outbf[r * DD + col] = f2bf_rne(v);
      }
    }
  }
}

// ------------------------------------------------- fused predictor GEMMs
__global__ __launch_bounds__(256) void gemm_pred2(
    const float* __restrict__ in,
    const unsigned short* __restrict__ W1h, const unsigned short* __restrict__ W1l,
    const unsigned short* __restrict__ W2h, const unsigned short* __restrict__ W2l,
    const float* __restrict__ bp1,
    unsigned short* __restrict__ P1bf, float* __restrict__ P2) {
  const int t = threadIdx.x;
  const int w = t >> 6, l = t & 63;
  const int lr = l & 15, kg = l >> 4;

  short8 B1h[2][4], B1l[2][4], B2h[2][4], B2l[2][4];
#pragma unroll
  for (int ct = 0; ct < 2; ++ct)
#pragma unroll
    for (int ks = 0; ks < 4; ++ks) {
      const size_t bo = (size_t)((w * 2 + ct) * 16 + lr) * DD + ks * 32 + kg * 8;
      B1h[ct][ks] = *(const short8*)(W1h + bo);
      B1l[ct][ks] = *(const short8*)(W1l + bo);
      B2h[ct][ks] = *(const short8*)(W2h + bo);
      B2l[ct][ks] = *(const short8*)(W2l + bo);
    }
  float bv0 = bp1[(w * 2 + 0) * 16 + lr];
  float bv1 = bp1[(w * 2 + 1) * 16 + lr];

  for (int c = blockIdx.x; c < NN / 16; c += gridDim.x) {
    const float* ap = in + ((size_t)c * 16 + lr) * DD + kg * 8;
    float va[4][8];
#pragma unroll
    for (int ks = 0; ks < 4; ++ks) {
      *(float4*)&va[ks][0] = *(const float4*)(ap + ks * 32);
      *(float4*)&va[ks][4] = *(const float4*)(ap + ks * 32 + 4);
    }
    short8 ah[4], al[4];
#pragma unroll
    for (int ks = 0; ks < 4; ++ks)
#pragma unroll
      for (int j = 0; j < 8; ++j) {
        unsigned short h = f2bf_rne(va[ks][j]);
        ah[ks][j] = (short)h;
        al[ks][j] = (short)f2bf_rne(va[ks][j] - bf2f(h));
      }
    f32x4 acc1[2], acc2[2];
    acc1[0] = (f32x4){0.f, 0.f, 0.f, 0.f};
    acc1[1] = (f32x4){0.f, 0.f, 0.f, 0.f};
    acc2[0] = (f32x4){0.f, 0.f, 0.f, 0.f};
    acc2[1] = (f32x4){0.f, 0.f, 0.f, 0.f};
#pragma unroll
    for (int ks = 0; ks < 4; ++ks) {
#pragma unroll
      for (int ct = 0; ct < 2; ++ct) {
        acc1[ct] = __builtin_amdgcn_mfma_f32_16x16x32_bf16(ah[ks], B1h[ct][ks], acc1[ct], 0, 0, 0);
        acc1[ct] = __builtin_amdgcn_mfma_f32_16x16x32_bf16(ah[ks], B1l[ct][ks], acc1[ct], 0, 0, 0);
        acc1[ct] = __builtin_amdgcn_mfma_f32_16x16x32_bf16(al[ks], B1h[ct][ks], acc1[ct], 0, 0, 0);
        acc2[ct] = __builtin_amdgcn_mfma_f32_16x16x32_bf16(ah[ks], B2h[ct][ks], acc2[ct], 0, 0, 0);
        acc2[ct] = __builtin_amdgcn_mfma_f32_16x16x32_bf16(ah[ks], B2l[ct][ks], acc2[ct], 0, 0, 0);
        acc2[ct] = __builtin_amdgcn_mfma_f32_16x16x32_bf16(al[ks], B2h[ct][ks], acc2[ct], 0, 0, 0);
      }
    }
    __syncthreads();   // all waves done reading chunk's A rows (P2 aliases in)
#pragma unroll
    for (int ct = 0; ct < 2; ++ct) {
      const int col = (w * 2 + ct) * 16 + lr;
      const float bb = ct ? bv1 : bv0;
#pragma unroll
      for (int q4 = 0; q4 < 4; ++q4) {
        const size_t r = (size_t)c * 16 + kg * 4 + q4;
        P1bf[r * DD + col] = f2bf_rne(acc1[ct][q4]);
        P2[r * DD + col] = acc2[ct][q4] + bb;
      }
    }
  }
}

// ------------------------------------------------- final edge pass (node-parallel)
__global__ __launch_bounds__(256) void edge_out(
    const unsigned short* __restrict__ P1bf, const float4* __restrict__ P2_4,
    const int* __restrict__ offs, const int4* __restrict__ recs,
    const float4* __restrict__ Wp2_4,
    const float* __restrict__ bp2, float* __restrict__ out) {
  const int slot = threadIdx.x >> 5, lane = threadIdx.x & 31;
  const int n = blockIdx.x * 8 + slot;
  if (n >= NN) return;
  const float4 w = Wp2_4[lane];
  const float bb = bp2[0];
  const float4 p2 = P2_4[(size_t)n * 32 + lane];
  const int beg = offs[n], end = offs[n + 1];
  int i = beg;
  for (; i + 4 <= end; i += 4) {
    float v[4];
    int eid[4];
#pragma unroll
    for (int u = 0; u < 4; ++u) {
      const int4 rec = recs[i + u];
      eid[u] = rec.y;
      const uint2 qq = *(const uint2*)(P1bf + (size_t)rec.x * DD + lane * 4);
      const float q0 = __uint_as_float(qq.x << 16);
      const float q1 = __uint_as_float(qq.x & 0xffff0000u);
      const float q2 = __uint_as_float(qq.y << 16);
      const float q3 = __uint_as_float(qq.y & 0xffff0000u);
      v[u] = fmaxf(q0 + p2.x, 0.f) * w.x + fmaxf(q1 + p2.y, 0.f) * w.y
           + fmaxf(q2 + p2.z, 0.f) * w.z + fmaxf(q3 + p2.w, 0.f) * w.w;
    }
#pragma unroll
    for (int m = 16; m >= 1; m >>= 1) {
#pragma unroll
      for (int u = 0; u < 4; ++u) v[u] += __shfl_xor(v[u], m, 64);
    }
    if (lane == 0) {
#pragma unroll
      for (int u = 0; u < 4; ++u) out[eid[u]] = v[u] + bb;
    }
  }
  for (; i < end; ++i) {
    const int4 rec = recs[i];
    const uint2 qq = *(const uint2*)(P1bf + (size_t)rec.x * DD + lane * 4);
    const float q0 = __uint_as_float(qq.x << 16);
    const float q1 = __uint_as_float(qq.x & 0xffff0000u);
    const float q2 = __uint_as_float(qq.y << 16);
    const float q3 = __uint_as_float(qq.y & 0xffff0000u);
    float v = fmaxf(q0 + p2.x, 0.f) * w.x + fmaxf(q1 + p2.y, 0.f) * w.y
            + fmaxf(q2 + p2.z, 0.f) * w.z + fmaxf(q3 + p2.w, 0.f) * w.w;
#pragma unroll
    for (int m = 16; m >= 1; m >>= 1) v += __shfl_xor(v, m, 64);
    if (lane == 0) out[rec.y] = v + bb;
  }
}

// ---------------------------------------------------------------- launch
extern "C" void kernel_launch(void* const* d_in, const int* in_sizes, int n_in,
                              void* d_out, int out_size, void* d_ws, size_t ws_size,
                              hipStream_t stream) {
  const float* x_in = (const float*)d_in[0];
  const float* ea   = (const float*)d_in[1];
  const int*   ei   = (const int*)d_in[2];   // integer inputs arrive as int32
  const float* Wl1 = (const float*)d_in[3];
  const float* bl1 = (const float*)d_in[4];
  const float* Wl2 = (const float*)d_in[5];
  const float* bl2 = (const float*)d_in[6];
  const float* We  = (const float*)d_in[7];
  const float* be  = (const float*)d_in[8];
  const float* Wp1 = (const float*)d_in[9];
  const float* bp1 = (const float*)d_in[10];
  const float* Wp2 = (const float*)d_in[11];
  const float* bp2 = (const float*)d_in[12];
  const int* src = ei;
  const int* dst = ei + NE;

  // workspace layout (~81 MB)
  float* bufA   = (float*)d_ws;                    // NN*DD f32
  float* bufB   = bufA + (size_t)NN * DD;          // NN*DD f32
  int*   cnt    = (int*)(bufB + (size_t)NN * DD);  // NN
  int*   offs   = cnt + NN;                        // NN+1
  int*   rank   = offs + NN + 1;                   // NE
  int4*  recs   = (int4*)(((uintptr_t)(rank + NE) + 15) & ~(uintptr_t)15); // NE
  unsigned short* WTh = (unsigned short*)(recs + NE);   // 8*16384 bf16
  unsigned short* WTl = WTh + 8 * 16384;                // 8*16384 bf16
  unsigned short* xbf = WTl + 8 * 16384;                // NN*DD bf16

  // CSR build + weight prep + x_in bf16 mirror (per-launch, deterministic)
  hipMemsetAsync(cnt, 0, NN * sizeof(int), stream);
  hist_rank<<<NE / 256, 256, 0, stream>>>(dst, cnt, rank);
  scan_nodes<<<1, 1024, 0, stream>>>(cnt, offs);
  csr_fill<<<NE / 256, 256, 0, stream>>>(src, dst, ea, offs, rank, recs);
  prep_w<<<(8 * 16384 + 255) / 256, 256, 0, stream>>>(Wl1, Wl2, Wp1, WTh, WTl);
  cvt_bf<<<(NN * DD / 2 + 255) / 256, 256, 0, stream>>>(
      (const float2*)x_in, (unsigned*)xbf, NN * DD / 2);

  const int GB = 1024;            // gemm grid: ~3 chunks/block
  const int AB = (NN + 7) / 8;    // 6250 blocks: 1 node/slot (max TLP)
#define WH(g) (WTh + (size_t)(g) * 16384)
#define WL(g) (WTl + (size_t)(g) * 16384)

  // L0: agg(x_in,xbf)->A; fused A->B (+xbf=x1)
  aggregate<<<AB, 256, 0, stream>>>(
      x_in, xbf, offs, recs, (const float4*)We, (const float4*)be, bufA);
  fused_mlp<true><<<GB, 256, 0, stream>>>(
      bufA, WH(0), WL(0), WH(3), WL(3), bl1, bl2, bufB, xbf);
  // L1: agg(B,xbf)->A; fused A->B (+xbf=x2)
  aggregate<<<AB, 256, 0, stream>>>(
      bufB, xbf, offs, recs, (const float4*)(We + DD), (const float4*)(be + DD), bufA);
  fused_mlp<true><<<GB, 256, 0, stream>>>(
      bufA, WH(1), WL(1), WH(4), WL(4), bl1 + DD, bl2 + DD, bufB, xbf);
  // L2: agg(B,xbf)->A; fused A->B (f32 only)
  aggregate<<<AB, 256, 0, stream>>>(
      bufB, xbf, offs, recs, (const float4*)(We + 2 * DD), (const float4*)(be + 2 * DD), bufA);
  fused_mlp<false><<<GB, 256, 0, stream>>>(
      bufA, WH(2), WL(2), WH(5), WL(5), bl1 + 2 * DD, bl2 + 2 * DD, bufB, nullptr);
  // predictor: xf = bufB.  P1 (bf16) -> bufA's storage; P2 (f32) -> bufB in-place.
  gemm_pred2<<<GB, 256, 0, stream>>>(bufB, WH(6), WL(6), WH(7), WL(7), bp1,
                                     (unsigned short*)bufA, bufB);
  edge_out<<<AB, 256, 0, stream>>>(
      (const unsigned short*)bufA, (const float4*)bufB, offs, recs,
      (const float4*)Wp2, bp2, (float*)d_out);
}

// Round 15
// 397.099 us; speedup vs baseline: 1.6854x; 1.0280x over previous
//
#include <hip/hip_runtime.h>

#define NN 50000
#define NE 800000
#define DD 128

typedef __attribute__((ext_vector_type(8))) short short8;
typedef __attribute__((ext_vector_type(4))) float f32x4;

__device__ inline unsigned short f2bf_rne(float f) {
  unsigned u = __float_as_uint(f);
  u += 0x7FFF + ((u >> 16) & 1);
  return (unsigned short)(u >> 16);
}
__device__ inline float bf2f(unsigned short h) {
  return __uint_as_float(((unsigned)h) << 16);
}

// ------------------------------------------------- fused prologue:
// zero cnt + weight transpose/split + x_in bf16 mirror (all independent).
__global__ __launch_bounds__(256) void prologue(
    const float* __restrict__ Wl1, const float* __restrict__ Wl2,
    const float* __restrict__ Wp1,
    unsigned short* __restrict__ WTh, unsigned short* __restrict__ WTl,
    const float2* __restrict__ xin2, unsigned* __restrict__ xbf2,
    int* __restrict__ cnt) {
  const int tid = blockIdx.x * 256 + threadIdx.x;
  if (tid < NN) cnt[tid] = 0;
  if (tid < 8 * 16384) {
    const int g = tid >> 14, idx = tid & 16383;
    const int n = idx >> 7, k = idx & 127;
    const float* s;
    if (g < 3) s = Wl1 + (size_t)g * 16384;
    else if (g < 6) s = Wl2 + (size_t)(g - 3) * 16384;
    else s = Wp1 + (size_t)(g - 6) * 16384;
    const float v = s[k * 128 + n];
    const unsigned short hi = f2bf_rne(v);
    WTh[tid] = hi;
    WTl[tid] = f2bf_rne(v - bf2f(hi));
  }
  if (tid < NN * DD / 2) {
    const float2 v = xin2[tid];
    xbf2[tid] = (unsigned)f2bf_rne(v.x) | ((unsigned)f2bf_rne(v.y) << 16);
  }
}

// ------------------------------------------------- CSR build: histogram + rank
__global__ __launch_bounds__(256) void hist_rank(const int* __restrict__ dst,
                                                 int* __restrict__ cnt,
                                                 int* __restrict__ rank) {
  int e = blockIdx.x * 256 + threadIdx.x;
  if (e < NE) rank[e] = atomicAdd(&cnt[dst[e]], 1);
}

// ------------------------------------------------- CSR build: scan (1 block)
__global__ __launch_bounds__(1024) void scan_nodes(const int* __restrict__ cnt,
                                                   int* __restrict__ offs) {
  __shared__ int wsum[16];
  __shared__ int wpre[16];
  const int t = threadIdx.x;
  const int lane = t & 63, wv = t >> 6;
  int carry = 0;
  for (int base = 0; base < NN; base += 8192) {
    const int i0 = base + t * 8;
    int4 a = make_int4(0, 0, 0, 0), b = make_int4(0, 0, 0, 0);
    if (i0 + 8 <= NN) {
      a = *(const int4*)(cnt + i0);
      b = *(const int4*)(cnt + i0 + 4);
    } else if (i0 < NN) {
      int tmp[8];
      for (int j = 0; j < 8; ++j) tmp[j] = (i0 + j < NN) ? cnt[i0 + j] : 0;
      a = make_int4(tmp[0], tmp[1], tmp[2], tmp[3]);
      b = make_int4(tmp[4], tmp[5], tmp[6], tmp[7]);
    }
    const int own = a.x + a.y + a.z + a.w + b.x + b.y + b.z + b.w;
    int inc = own;
#pragma unroll
    for (int d = 1; d < 64; d <<= 1) {
      int v = __shfl_up(inc, d, 64);
      if (lane >= d) inc += v;
    }
    if (lane == 63) wsum[wv] = inc;
    __syncthreads();
    if (t < 16) {
      int v = wsum[t];
      int p = v;
#pragma unroll
      for (int d = 1; d < 16; d <<= 1) {
        int u = __shfl_up(p, d, 16);
        if (t >= d) p += u;
      }
      wpre[t] = p - v;
      if (t == 15) wsum[15] = p;
    }
    __syncthreads();
    int run = carry + wpre[wv] + inc - own;
    const int o0 = run,      o1 = o0 + a.x, o2 = o1 + a.y, o3 = o2 + a.z;
    const int o4 = o3 + a.w, o5 = o4 + b.x, o6 = o5 + b.y, o7 = o6 + b.z;
    if (i0 + 8 <= NN) {
      *(int4*)(offs + i0)     = make_int4(o0, o1, o2, o3);
      *(int4*)(offs + i0 + 4) = make_int4(o4, o5, o6, o7);
    } else if (i0 < NN) {
      const int o[8] = {o0, o1, o2, o3, o4, o5, o6, o7};
      for (int j = 0; j < 8; ++j)
        if (i0 + j < NN) offs[i0 + j] = o[j];
    }
    carry += wsum[15];
    __syncthreads();
  }
  if (t == 0) offs[NN] = carry;
}

// ------------------------------------------------- CSR build: fill (NO atomics)
__global__ __launch_bounds__(256) void csr_fill(
    const int* __restrict__ src, const int* __restrict__ dst,
    const float* __restrict__ ea, const int* __restrict__ offs,
    const int* __restrict__ rank, int4* __restrict__ recs) {
  int e = blockIdx.x * 256 + threadIdx.x;
  if (e >= NE) return;
  int pos = offs[dst[e]] + rank[e];
  recs[pos] = make_int4(src[e], e, __float_as_int(ea[e]), 0);
}

// ------------------------------------------------- per-node aggregation
// One node per 32-lane slot; 8-deep independent gather unroll.
__global__ __launch_bounds__(256) void aggregate(
    const float* __restrict__ x, const unsigned short* __restrict__ xbf,
    const int* __restrict__ offs, const int4* __restrict__ recs,
    const float4* __restrict__ We4, const float4* __restrict__ be4,
    float* __restrict__ out) {
  const int slot = threadIdx.x >> 5, lane = threadIdx.x & 31;
  const int n = blockIdx.x * 8 + slot;
  if (n >= NN) return;
  const float4 wv = We4[lane], bv = be4[lane];
  float4 a0 = ((const float4*)(x + (size_t)n * DD))[lane];
  float4 a1 = make_float4(0.f, 0.f, 0.f, 0.f);
  float4 a2 = make_float4(0.f, 0.f, 0.f, 0.f);
  float4 a3 = make_float4(0.f, 0.f, 0.f, 0.f);
  const int beg = offs[n], end = offs[n + 1];
  int i = beg;
#define ACCQ(acc, rec, qq)                                                    \
  {                                                                           \
    const float ee = __int_as_float((rec).z);                                 \
    const float g0 = __uint_as_float((qq).x << 16);                           \
    const float g1 = __uint_as_float((qq).x & 0xffff0000u);                   \
    const float g2 = __uint_as_float((qq).y << 16);                           \
    const float g3 = __uint_as_float((qq).y & 0xffff0000u);                   \
    acc.x += fmaxf(fmaf(ee, wv.x, bv.x) + g0, 0.f);                           \
    acc.y += fmaxf(fmaf(ee, wv.y, bv.y) + g1, 0.f);                           \
    acc.z += fmaxf(fmaf(ee, wv.z, bv.z) + g2, 0.f);                           \
    acc.w += fmaxf(fmaf(ee, wv.w, bv.w) + g3, 0.f);                           \
  }
  for (; i + 8 <= end; i += 8) {
    int4 r[8];
#pragma unroll
    for (int u = 0; u < 8; ++u) r[u] = recs[i + u];
    uint2 q[8];
#pragma unroll
    for (int u = 0; u < 8; ++u)
      q[u] = *(const uint2*)(xbf + (size_t)r[u].x * DD + lane * 4);
    ACCQ(a0, r[0], q[0]) ACCQ(a1, r[1], q[1]) ACCQ(a2, r[2], q[2]) ACCQ(a3, r[3], q[3])
    ACCQ(a0, r[4], q[4]) ACCQ(a1, r[5], q[5]) ACCQ(a2, r[6], q[6]) ACCQ(a3, r[7], q[7])
  }
  for (; i + 4 <= end; i += 4) {
    int4 r[4];
#pragma unroll
    for (int u = 0; u < 4; ++u) r[u] = recs[i + u];
    uint2 q[4];
#pragma unroll
    for (int u = 0; u < 4; ++u)
      q[u] = *(const uint2*)(xbf + (size_t)r[u].x * DD + lane * 4);
    ACCQ(a0, r[0], q[0]) ACCQ(a1, r[1], q[1]) ACCQ(a2, r[2], q[2]) ACCQ(a3, r[3], q[3])
  }
  for (; i < end; ++i) {
    const int4 r0 = recs[i];
    const uint2 q0 = *(const uint2*)(xbf + (size_t)r0.x * DD + lane * 4);
    ACCQ(a0, r0, q0)
  }
#undef ACCQ
  a0.x += a1.x + a2.x + a3.x;
  a0.y += a1.y + a2.y + a3.y;
  a0.z += a1.z + a2.z + a3.z;
  a0.w += a1.w + a2.w + a3.w;
  ((float4*)(out + (size_t)n * DD))[lane] = a0;
}

// ------------------------------------------------- fused layer MLP (B1+B2 in regs)
template <bool DUALBF>
__global__ __launch_bounds__(256) void fused_mlp(
    const float* __restrict__ in,
    const unsigned short* __restrict__ W1h, const unsigned short* __restrict__ W1l,
    const unsigned short* __restrict__ W2h, const unsigned short* __restrict__ W2l,
    const float* __restrict__ b1, const float* __restrict__ b2,
    float* __restrict__ out, unsigned short* __restrict__ outbf) {
  __shared__ float hl[16][132];
  const int t = threadIdx.x;
  const int w = t >> 6, l = t & 63;
  const int lr = l & 15, kg = l >> 4;

  short8 B1h_[2][4], B1l_[2][4], B2h_[2][4], B2l_[2][4];
#pragma unroll
  for (int ct = 0; ct < 2; ++ct)
#pragma unroll
    for (int ks = 0; ks < 4; ++ks) {
      const size_t bo = (size_t)((w * 2 + ct) * 16 + lr) * DD + ks * 32 + kg * 8;
      B1h_[ct][ks] = *(const short8*)(W1h + bo);
      B1l_[ct][ks] = *(const short8*)(W1l + bo);
      B2h_[ct][ks] = *(const short8*)(W2h + bo);
      B2l_[ct][ks] = *(const short8*)(W2l + bo);
    }
  const float b1v0 = b1[(w * 2 + 0) * 16 + lr];
  const float b1v1 = b1[(w * 2 + 1) * 16 + lr];
  const float b2v0 = b2[(w * 2 + 0) * 16 + lr];
  const float b2v1 = b2[(w * 2 + 1) * 16 + lr];

  for (int c = blockIdx.x; c < NN / 16; c += gridDim.x) {
    f32x4 acc[2];
    // ---- GEMM1: A from global f32
    {
      const float* ap = in + ((size_t)c * 16 + lr) * DD + kg * 8;
      float va[4][8];
#pragma unroll
      for (int ks = 0; ks < 4; ++ks) {
        *(float4*)&va[ks][0] = *(const float4*)(ap + ks * 32);
        *(float4*)&va[ks][4] = *(const float4*)(ap + ks * 32 + 4);
      }
      short8 ah[4], al[4];
#pragma unroll
      for (int ks = 0; ks < 4; ++ks)
#pragma unroll
        for (int j = 0; j < 8; ++j) {
          unsigned short h = f2bf_rne(va[ks][j]);
          ah[ks][j] = (short)h;
          al[ks][j] = (short)f2bf_rne(va[ks][j] - bf2f(h));
        }
      acc[0] = (f32x4){0.f, 0.f, 0.f, 0.f};
      acc[1] = (f32x4){0.f, 0.f, 0.f, 0.f};
#pragma unroll
      for (int ks = 0; ks < 4; ++ks)
#pragma unroll
        for (int ct = 0; ct < 2; ++ct) {
          acc[ct] = __builtin_amdgcn_mfma_f32_16x16x32_bf16(ah[ks], B1h_[ct][ks], acc[ct], 0, 0, 0);
          acc[ct] = __builtin_amdgcn_mfma_f32_16x16x32_bf16(ah[ks], B1l_[ct][ks], acc[ct], 0, 0, 0);
          acc[ct] = __builtin_amdgcn_mfma_f32_16x16x32_bf16(al[ks], B1h_[ct][ks], acc[ct], 0, 0, 0);
        }
    }
    // ---- h -> LDS
    __syncthreads();
#pragma unroll
    for (int ct = 0; ct < 2; ++ct) {
      const float bb = ct ? b1v1 : b1v0;
      const int col = (w * 2 + ct) * 16 + lr;
#pragma unroll
      for (int q = 0; q < 4; ++q)
        hl[kg * 4 + q][col] = fmaxf(acc[ct][q] + bb, 0.f);
    }
    __syncthreads();
    // ---- GEMM2: A from LDS
    {
      float va[4][8];
#pragma unroll
      for (int ks = 0; ks < 4; ++ks) {
        *(float4*)&va[ks][0] = *(const float4*)&hl[lr][ks * 32 + kg * 8];
        *(float4*)&va[ks][4] = *(const float4*)&hl[lr][ks * 32 + kg * 8 + 4];
      }
      short8 ah[4], al[4];
#pragma unroll
      for (int ks = 0; ks < 4; ++ks)
#pragma unroll
        for (int j = 0; j < 8; ++j) {
          unsigned short h = f2bf_rne(va[ks][j]);
          ah[ks][j] = (short)h;
          al[ks][j] = (short)f2bf_rne(va[ks][j] - bf2f(h));
        }
      acc[0] = (f32x4){0.f, 0.f, 0.f, 0.f};
      acc[1] = (f32x4){0.f, 0.f, 0.f, 0.f};
#pragma unroll
      for (int ks = 0; ks < 4; ++ks)
#pragma unroll
        for (int ct = 0; ct < 2; ++ct) {
          acc[ct] = __builtin_amdgcn_mfma_f32_16x16x32_bf16(ah[ks], B2h_[ct][ks], acc[ct], 0, 0, 0);
          acc[ct] = __builtin_amdgcn_mfma_f32_16x16x32_bf16(ah[ks], B2l_[ct][ks], acc[ct], 0, 0, 0);
          acc[ct] = __builtin_amdgcn_mfma_f32_16x16x32_bf16(al[ks], B2h_[ct][ks], acc[ct], 0, 0, 0);
        }
    }
    // ---- epilogue
#pragma unroll
    for (int ct = 0; ct < 2; ++ct) {
      const float bb = ct ? b2v1 : b2v0;
      const int col = (w * 2 + ct) * 16 + lr;
#pragma unroll
      for (int q = 0; q < 4; ++q) {
        const float v = fmaxf(acc[ct][q] + bb, 0.f);
        const size_t r = (size_t)c * 16 + kg * 4 + q;
        out[r * DD + col] = v;
        if (DUALBF) outbf[r * DD + col] = f2bf_rne(v);
      }
    }
  }
}

// ------------------------------------------------- fused predictor GEMMs
// P1, P2 BOTH stored bf16 (halves edge_out traffic); no aliasing, no barrier.
__global__ __launch_bounds__(256) void gemm_pred2(
    const float* __restrict__ in,
    const unsigned short* __restrict__ W1h, const unsigned short* __restrict__ W1l,
    const unsigned short* __restrict__ W2h, const unsigned short* __restrict__ W2l,
    const float* __restrict__ bp1,
    unsigned short* __restrict__ P1bf, unsigned short* __restrict__ P2bf) {
  const int t = threadIdx.x;
  const int w = t >> 6, l = t & 63;
  const int lr = l & 15, kg = l >> 4;

  short8 B1h[2][4], B1l[2][4], B2h[2][4], B2l[2][4];
#pragma unroll
  for (int ct = 0; ct < 2; ++ct)
#pragma unroll
    for (int ks = 0; ks < 4; ++ks) {
      const size_t bo = (size_t)((w * 2 + ct) * 16 + lr) * DD + ks * 32 + kg * 8;
      B1h[ct][ks] = *(const short8*)(W1h + bo);
      B1l[ct][ks] = *(const short8*)(W1l + bo);
      B2h[ct][ks] = *(const short8*)(W2h + bo);
      B2l[ct][ks] = *(const short8*)(W2l + bo);
    }
  float bv0 = bp1[(w * 2 + 0) * 16 + lr];
  float bv1 = bp1[(w * 2 + 1) * 16 + lr];

  for (int c = blockIdx.x; c < NN / 16; c += gridDim.x) {
    const float* ap = in + ((size_t)c * 16 + lr) * DD + kg * 8;
    float va[4][8];
#pragma unroll
    for (int ks = 0; ks < 4; ++ks) {
      *(float4*)&va[ks][0] = *(const float4*)(ap + ks * 32);
      *(float4*)&va[ks][4] = *(const float4*)(ap + ks * 32 + 4);
    }
    short8 ah[4], al[4];
#pragma unroll
    for (int ks = 0; ks < 4; ++ks)
#pragma unroll
      for (int j = 0; j < 8; ++j) {
        unsigned short h = f2bf_rne(va[ks][j]);
        ah[ks][j] = (short)h;
        al[ks][j] = (short)f2bf_rne(va[ks][j] - bf2f(h));
      }
    f32x4 acc1[2], acc2[2];
    acc1[0] = (f32x4){0.f, 0.f, 0.f, 0.f};
    acc1[1] = (f32x4){0.f, 0.f, 0.f, 0.f};
    acc2[0] = (f32x4){0.f, 0.f, 0.f, 0.f};
    acc2[1] = (f32x4){0.f, 0.f, 0.f, 0.f};
#pragma unroll
    for (int ks = 0; ks < 4; ++ks) {
#pragma unroll
      for (int ct = 0; ct < 2; ++ct) {
        acc1[ct] = __builtin_amdgcn_mfma_f32_16x16x32_bf16(ah[ks], B1h[ct][ks], acc1[ct], 0, 0, 0);
        acc1[ct] = __builtin_amdgcn_mfma_f32_16x16x32_bf16(ah[ks], B1l[ct][ks], acc1[ct], 0, 0, 0);
        acc1[ct] = __builtin_amdgcn_mfma_f32_16x16x32_bf16(al[ks], B1h[ct][ks], acc1[ct], 0, 0, 0);
        acc2[ct] = __builtin_amdgcn_mfma_f32_16x16x32_bf16(ah[ks], B2h[ct][ks], acc2[ct], 0, 0, 0);
        acc2[ct] = __builtin_amdgcn_mfma_f32_16x16x32_bf16(ah[ks], B2l[ct][ks], acc2[ct], 0, 0, 0);
        acc2[ct] = __builtin_amdgcn_mfma_f32_16x16x32_bf16(al[ks], B2h[ct][ks], acc2[ct], 0, 0, 0);
      }
    }
#pragma unroll
    for (int ct = 0; ct < 2; ++ct) {
      const int col = (w * 2 + ct) * 16 + lr;
      const float bb = ct ? bv1 : bv0;
#pragma unroll
      for (int q4 = 0; q4 < 4; ++q4) {
        const size_t r = (size_t)c * 16 + kg * 4 + q4;
        P1bf[r * DD + col] = f2bf_rne(acc1[ct][q4]);
        P2bf[r * DD + col] = f2bf_rne(acc2[ct][q4] + bb);
      }
    }
  }
}

// ------------------------------------------------- final edge pass (node-parallel)
// 8-deep gather unroll; P1 and P2 both bf16.
__global__ __launch_bounds__(256) void edge_out(
    const unsigned short* __restrict__ P1bf, const unsigned short* __restrict__ P2bf,
    const int* __restrict__ offs, const int4* __restrict__ recs,
    const float4* __restrict__ Wp2_4,
    const float* __restrict__ bp2, float* __restrict__ out) {
  const int slot = threadIdx.x >> 5, lane = threadIdx.x & 31;
  const int n = blockIdx.x * 8 + slot;
  if (n >= NN) return;
  const float4 w = Wp2_4[lane];
  const float bb = bp2[0];
  const uint2 pq = *(const uint2*)(P2bf + (size_t)n * DD + lane * 4);
  float4 p2;
  p2.x = __uint_as_float(pq.x << 16);
  p2.y = __uint_as_float(pq.x & 0xffff0000u);
  p2.z = __uint_as_float(pq.y << 16);
  p2.w = __uint_as_float(pq.y & 0xffff0000u);
  const int beg = offs[n], end = offs[n + 1];
  int i = beg;
#define EDGEV(vv, qq)                                                         \
  {                                                                           \
    const float q0 = __uint_as_float((qq).x << 16);                           \
    const float q1 = __uint_as_float((qq).x & 0xffff0000u);                   \
    const float q2 = __uint_as_float((qq).y << 16);                           \
    const float q3 = __uint_as_float((qq).y & 0xffff0000u);                   \
    vv = fmaxf(q0 + p2.x, 0.f) * w.x + fmaxf(q1 + p2.y, 0.f) * w.y            \
       + fmaxf(q2 + p2.z, 0.f) * w.z + fmaxf(q3 + p2.w, 0.f) * w.w;           \
  }
  for (; i + 8 <= end; i += 8) {
    int4 r[8];
#pragma unroll
    for (int u = 0; u < 8; ++u) r[u] = recs[i + u];
    uint2 q[8];
#pragma unroll
    for (int u = 0; u < 8; ++u)
      q[u] = *(const uint2*)(P1bf + (size_t)r[u].x * DD + lane * 4);
    float v[8];
#pragma unroll
    for (int u = 0; u < 8; ++u) EDGEV(v[u], q[u])
#pragma unroll
    for (int m = 16; m >= 1; m >>= 1) {
#pragma unroll
      for (int u = 0; u < 8; ++u) v[u] += __shfl_xor(v[u], m, 64);
    }
    if (lane == 0) {
#pragma unroll
      for (int u = 0; u < 8; ++u) out[r[u].y] = v[u] + bb;
    }
  }
  for (; i + 4 <= end; i += 4) {
    int4 r[4];
#pragma unroll
    for (int u = 0; u < 4; ++u) r[u] = recs[i + u];
    uint2 q[4];
#pragma unroll
    for (int u = 0; u < 4; ++u)
      q[u] = *(const uint2*)(P1bf + (size_t)r[u].x * DD + lane * 4);
    float v[4];
#pragma unroll
    for (int u = 0; u < 4; ++u) EDGEV(v[u], q[u])
#pragma unroll
    for (int m = 16; m >= 1; m >>= 1) {
#pragma unroll
      for (int u = 0; u < 4; ++u) v[u] += __shfl_xor(v[u], m, 64);
    }
    if (lane == 0) {
#pragma unroll
      for (int u = 0; u < 4; ++u) out[r[u].y] = v[u] + bb;
    }
  }
  for (; i < end; ++i) {
    const int4 rec = recs[i];
    const uint2 qq = *(const uint2*)(P1bf + (size_t)rec.x * DD + lane * 4);
    float v;
    EDGEV(v, qq)
#pragma unroll
    for (int m = 16; m >= 1; m >>= 1) v += __shfl_xor(v, m, 64);
    if (lane == 0) out[rec.y] = v + bb;
  }
#undef EDGEV
}

// ---------------------------------------------------------------- launch
extern "C" void kernel_launch(void* const* d_in, const int* in_sizes, int n_in,
                              void* d_out, int out_size, void* d_ws, size_t ws_size,
                              hipStream_t stream) {
  const float* x_in = (const float*)d_in[0];
  const float* ea   = (const float*)d_in[1];
  const int*   ei   = (const int*)d_in[2];   // integer inputs arrive as int32
  const float* Wl1 = (const float*)d_in[3];
  const float* bl1 = (const float*)d_in[4];
  const float* Wl2 = (const float*)d_in[5];
  const float* bl2 = (const float*)d_in[6];
  const float* We  = (const float*)d_in[7];
  const float* be  = (const float*)d_in[8];
  const float* Wp1 = (const float*)d_in[9];
  const float* bp1 = (const float*)d_in[10];
  const float* Wp2 = (const float*)d_in[11];
  const float* bp2 = (const float*)d_in[12];
  const int* src = ei;
  const int* dst = ei + NE;

  // workspace layout (~81 MB)
  float* bufA   = (float*)d_ws;                    // NN*DD f32
  float* bufB   = bufA + (size_t)NN * DD;          // NN*DD f32
  int*   cnt    = (int*)(bufB + (size_t)NN * DD);  // NN
  int*   offs   = cnt + NN;                        // NN+1
  int*   rank   = offs + NN + 1;                   // NE
  int4*  recs   = (int4*)(((uintptr_t)(rank + NE) + 15) & ~(uintptr_t)15); // NE
  unsigned short* WTh = (unsigned short*)(recs + NE);   // 8*16384 bf16
  unsigned short* WTl = WTh + 8 * 16384;                // 8*16384 bf16
  unsigned short* xbf = WTl + 8 * 16384;                // NN*DD bf16 (later: P2bf)

  // fused prologue + CSR build (per-launch, deterministic)
  prologue<<<(NN * DD / 2 + 255) / 256, 256, 0, stream>>>(
      Wl1, Wl2, Wp1, WTh, WTl, (const float2*)x_in, (unsigned*)xbf, cnt);
  hist_rank<<<NE / 256, 256, 0, stream>>>(dst, cnt, rank);
  scan_nodes<<<1, 1024, 0, stream>>>(cnt, offs);
  csr_fill<<<NE / 256, 256, 0, stream>>>(src, dst, ea, offs, rank, recs);

  const int GB = 1024;            // gemm grid: ~3 chunks/block
  const int AB = (NN + 7) / 8;    // 6250 blocks: 1 node/slot (max TLP)
#define WH(g) (WTh + (size_t)(g) * 16384)
#define WL(g) (WTl + (size_t)(g) * 16384)

  // L0: agg(x_in,xbf)->A; fused A->B (+xbf=x1)
  aggregate<<<AB, 256, 0, stream>>>(
      x_in, xbf, offs, recs, (const float4*)We, (const float4*)be, bufA);
  fused_mlp<true><<<GB, 256, 0, stream>>>(
      bufA, WH(0), WL(0), WH(3), WL(3), bl1, bl2, bufB, xbf);
  // L1: agg(B,xbf)->A; fused A->B (+xbf=x2)
  aggregate<<<AB, 256, 0, stream>>>(
      bufB, xbf, offs, recs, (const float4*)(We + DD), (const float4*)(be + DD), bufA);
  fused_mlp<true><<<GB, 256, 0, stream>>>(
      bufA, WH(1), WL(1), WH(4), WL(4), bl1 + DD, bl2 + DD, bufB, xbf);
  // L2: agg(B,xbf)->A; fused A->B (f32 only)
  aggregate<<<AB, 256, 0, stream>>>(
      bufB, xbf, offs, recs, (const float4*)(We + 2 * DD), (const float4*)(be + 2 * DD), bufA);
  fused_mlp<false><<<GB, 256, 0, stream>>>(
      bufA, WH(2), WL(2), WH(5), WL(5), bl1 + 2 * DD, bl2 + 2 * DD, bufB, nullptr);
  // predictor: xf = bufB.  P1bf -> bufA storage; P2bf -> xbf (free after L2 agg).
  gemm_pred2<<<GB, 256, 0, stream>>>(bufB, WH(6), WL(6), WH(7), WL(7), bp1,
                                     (unsigned short*)bufA, xbf);
  edge_out<<<AB, 256, 0, stream>>>(
      (const unsigned short*)bufA, xbf, offs, recs,
      (const float4*)Wp2, bp2, (float*)d_out);
}

// Round 16
// 386.085 us; speedup vs baseline: 1.7335x; 1.0285x over previous
//
#include <hip/hip_runtime.h>

#define NN 50000
#define NE 800000
#define DD 128

typedef __attribute__((ext_vector_type(8))) short short8;
typedef __attribute__((ext_vector_type(4))) float f32x4;

__device__ inline unsigned short f2bf_rne(float f) {
  unsigned u = __float_as_uint(f);
  u += 0x7FFF + ((u >> 16) & 1);
  return (unsigned short)(u >> 16);
}
__device__ inline float bf2f(unsigned short h) {
  return __uint_as_float(((unsigned)h) << 16);
}

// ------------------------------------------------- fused prologue:
// zero cnt + weight transpose/split + x_in bf16 mirror (all independent).
__global__ __launch_bounds__(256) void prologue(
    const float* __restrict__ Wl1, const float* __restrict__ Wl2,
    const float* __restrict__ Wp1,
    unsigned short* __restrict__ WTh, unsigned short* __restrict__ WTl,
    const float2* __restrict__ xin2, unsigned* __restrict__ xbf2,
    int* __restrict__ cnt) {
  const int tid = blockIdx.x * 256 + threadIdx.x;
  if (tid < NN) cnt[tid] = 0;
  if (tid < 8 * 16384) {
    const int g = tid >> 14, idx = tid & 16383;
    const int n = idx >> 7, k = idx & 127;
    const float* s;
    if (g < 3) s = Wl1 + (size_t)g * 16384;
    else if (g < 6) s = Wl2 + (size_t)(g - 3) * 16384;
    else s = Wp1 + (size_t)(g - 6) * 16384;
    const float v = s[k * 128 + n];
    const unsigned short hi = f2bf_rne(v);
    WTh[tid] = hi;
    WTl[tid] = f2bf_rne(v - bf2f(hi));
  }
  if (tid < NN * DD / 2) {
    const float2 v = xin2[tid];
    xbf2[tid] = (unsigned)f2bf_rne(v.x) | ((unsigned)f2bf_rne(v.y) << 16);
  }
}

// ------------------------------------------------- CSR build: histogram + rank
__global__ __launch_bounds__(256) void hist_rank(const int* __restrict__ dst,
                                                 int* __restrict__ cnt,
                                                 int* __restrict__ rank) {
  int e = blockIdx.x * 256 + threadIdx.x;
  if (e < NE) rank[e] = atomicAdd(&cnt[dst[e]], 1);
}

// ------------------------------------------------- CSR build: scan (1 block)
__global__ __launch_bounds__(1024) void scan_nodes(const int* __restrict__ cnt,
                                                   int* __restrict__ offs) {
  __shared__ int wsum[16];
  __shared__ int wpre[16];
  const int t = threadIdx.x;
  const int lane = t & 63, wv = t >> 6;
  int carry = 0;
  for (int base = 0; base < NN; base += 8192) {
    const int i0 = base + t * 8;
    int4 a = make_int4(0, 0, 0, 0), b = make_int4(0, 0, 0, 0);
    if (i0 + 8 <= NN) {
      a = *(const int4*)(cnt + i0);
      b = *(const int4*)(cnt + i0 + 4);
    } else if (i0 < NN) {
      int tmp[8];
      for (int j = 0; j < 8; ++j) tmp[j] = (i0 + j < NN) ? cnt[i0 + j] : 0;
      a = make_int4(tmp[0], tmp[1], tmp[2], tmp[3]);
      b = make_int4(tmp[4], tmp[5], tmp[6], tmp[7]);
    }
    const int own = a.x + a.y + a.z + a.w + b.x + b.y + b.z + b.w;
    int inc = own;
#pragma unroll
    for (int d = 1; d < 64; d <<= 1) {
      int v = __shfl_up(inc, d, 64);
      if (lane >= d) inc += v;
    }
    if (lane == 63) wsum[wv] = inc;
    __syncthreads();
    if (t < 16) {
      int v = wsum[t];
      int p = v;
#pragma unroll
      for (int d = 1; d < 16; d <<= 1) {
        int u = __shfl_up(p, d, 16);
        if (t >= d) p += u;
      }
      wpre[t] = p - v;
      if (t == 15) wsum[15] = p;
    }
    __syncthreads();
    int run = carry + wpre[wv] + inc - own;
    const int o0 = run,      o1 = o0 + a.x, o2 = o1 + a.y, o3 = o2 + a.z;
    const int o4 = o3 + a.w, o5 = o4 + b.x, o6 = o5 + b.y, o7 = o6 + b.z;
    if (i0 + 8 <= NN) {
      *(int4*)(offs + i0)     = make_int4(o0, o1, o2, o3);
      *(int4*)(offs + i0 + 4) = make_int4(o4, o5, o6, o7);
    } else if (i0 < NN) {
      const int o[8] = {o0, o1, o2, o3, o4, o5, o6, o7};
      for (int j = 0; j < 8; ++j)
        if (i0 + j < NN) offs[i0 + j] = o[j];
    }
    carry += wsum[15];
    __syncthreads();
  }
  if (t == 0) offs[NN] = carry;
}

// ------------------------------------------------- CSR build: fill (NO atomics)
__global__ __launch_bounds__(256) void csr_fill(
    const int* __restrict__ src, const int* __restrict__ dst,
    const float* __restrict__ ea, const int* __restrict__ offs,
    const int* __restrict__ rank, int4* __restrict__ recs) {
  int e = blockIdx.x * 256 + threadIdx.x;
  if (e >= NE) return;
  int pos = offs[dst[e]] + rank[e];
  recs[pos] = make_int4(src[e], e, __float_as_int(ea[e]), 0);
}

// ------------------------------------------------- per-node aggregation
// Self + neighbors both from bf16 mirror (single per-layer quantization).
// One node per 32-lane slot; 8-deep independent gather unroll.
__global__ __launch_bounds__(256) void aggregate(
    const unsigned short* __restrict__ xbf,
    const int* __restrict__ offs, const int4* __restrict__ recs,
    const float4* __restrict__ We4, const float4* __restrict__ be4,
    float* __restrict__ out) {
  const int slot = threadIdx.x >> 5, lane = threadIdx.x & 31;
  const int n = blockIdx.x * 8 + slot;
  if (n >= NN) return;
  const float4 wv = We4[lane], bv = be4[lane];
  const uint2 sq = *(const uint2*)(xbf + (size_t)n * DD + lane * 4);
  float4 a0, a1, a2, a3;
  a0.x = __uint_as_float(sq.x << 16);
  a0.y = __uint_as_float(sq.x & 0xffff0000u);
  a0.z = __uint_as_float(sq.y << 16);
  a0.w = __uint_as_float(sq.y & 0xffff0000u);
  a1 = make_float4(0.f, 0.f, 0.f, 0.f);
  a2 = make_float4(0.f, 0.f, 0.f, 0.f);
  a3 = make_float4(0.f, 0.f, 0.f, 0.f);
  const int beg = offs[n], end = offs[n + 1];
  int i = beg;
#define ACCQ(acc, rec, qq)                                                    \
  {                                                                           \
    const float ee = __int_as_float((rec).z);                                 \
    const float g0 = __uint_as_float((qq).x << 16);                           \
    const float g1 = __uint_as_float((qq).x & 0xffff0000u);                   \
    const float g2 = __uint_as_float((qq).y << 16);                           \
    const float g3 = __uint_as_float((qq).y & 0xffff0000u);                   \
    acc.x += fmaxf(fmaf(ee, wv.x, bv.x) + g0, 0.f);                           \
    acc.y += fmaxf(fmaf(ee, wv.y, bv.y) + g1, 0.f);                           \
    acc.z += fmaxf(fmaf(ee, wv.z, bv.z) + g2, 0.f);                           \
    acc.w += fmaxf(fmaf(ee, wv.w, bv.w) + g3, 0.f);                           \
  }
  for (; i + 8 <= end; i += 8) {
    int4 r[8];
#pragma unroll
    for (int u = 0; u < 8; ++u) r[u] = recs[i + u];
    uint2 q[8];
#pragma unroll
    for (int u = 0; u < 8; ++u)
      q[u] = *(const uint2*)(xbf + (size_t)r[u].x * DD + lane * 4);
    ACCQ(a0, r[0], q[0]) ACCQ(a1, r[1], q[1]) ACCQ(a2, r[2], q[2]) ACCQ(a3, r[3], q[3])
    ACCQ(a0, r[4], q[4]) ACCQ(a1, r[5], q[5]) ACCQ(a2, r[6], q[6]) ACCQ(a3, r[7], q[7])
  }
  for (; i + 4 <= end; i += 4) {
    int4 r[4];
#pragma unroll
    for (int u = 0; u < 4; ++u) r[u] = recs[i + u];
    uint2 q[4];
#pragma unroll
    for (int u = 0; u < 4; ++u)
      q[u] = *(const uint2*)(xbf + (size_t)r[u].x * DD + lane * 4);
    ACCQ(a0, r[0], q[0]) ACCQ(a1, r[1], q[1]) ACCQ(a2, r[2], q[2]) ACCQ(a3, r[3], q[3])
  }
  for (; i < end; ++i) {
    const int4 r0 = recs[i];
    const uint2 q0 = *(const uint2*)(xbf + (size_t)r0.x * DD + lane * 4);
    ACCQ(a0, r0, q0)
  }
#undef ACCQ
  a0.x += a1.x + a2.x + a3.x;
  a0.y += a1.y + a2.y + a3.y;
  a0.z += a1.z + a2.z + a3.z;
  a0.w += a1.w + a2.w + a3.w;
  ((float4*)(out + (size_t)n * DD))[lane] = a0;
}

// ------------------------------------------------- fused layer MLP (B1+B2 in regs)
// F32OUT: write f32 output (for pred GEMM A). BFOUT: write bf16 mirror.
template <bool F32OUT, bool BFOUT>
__global__ __launch_bounds__(256) void fused_mlp(
    const float* __restrict__ in,
    const unsigned short* __restrict__ W1h, const unsigned short* __restrict__ W1l,
    const unsigned short* __restrict__ W2h, const unsigned short* __restrict__ W2l,
    const float* __restrict__ b1, const float* __restrict__ b2,
    float* __restrict__ out, unsigned short* __restrict__ outbf) {
  __shared__ float hl[16][132];
  const int t = threadIdx.x;
  const int w = t >> 6, l = t & 63;
  const int lr = l & 15, kg = l >> 4;

  short8 B1h_[2][4], B1l_[2][4], B2h_[2][4], B2l_[2][4];
#pragma unroll
  for (int ct = 0; ct < 2; ++ct)
#pragma unroll
    for (int ks = 0; ks < 4; ++ks) {
      const size_t bo = (size_t)((w * 2 + ct) * 16 + lr) * DD + ks * 32 + kg * 8;
      B1h_[ct][ks] = *(const short8*)(W1h + bo);
      B1l_[ct][ks] = *(const short8*)(W1l + bo);
      B2h_[ct][ks] = *(const short8*)(W2h + bo);
      B2l_[ct][ks] = *(const short8*)(W2l + bo);
    }
  const float b1v0 = b1[(w * 2 + 0) * 16 + lr];
  const float b1v1 = b1[(w * 2 + 1) * 16 + lr];
  const float b2v0 = b2[(w * 2 + 0) * 16 + lr];
  const float b2v1 = b2[(w * 2 + 1) * 16 + lr];

  for (int c = blockIdx.x; c < NN / 16; c += gridDim.x) {
    f32x4 acc[2];
    // ---- GEMM1: A from global f32
    {
      const float* ap = in + ((size_t)c * 16 + lr) * DD + kg * 8;
      float va[4][8];
#pragma unroll
      for (int ks = 0; ks < 4; ++ks) {
        *(float4*)&va[ks][0] = *(const float4*)(ap + ks * 32);
        *(float4*)&va[ks][4] = *(const float4*)(ap + ks * 32 + 4);
      }
      short8 ah[4], al[4];
#pragma unroll
      for (int ks = 0; ks < 4; ++ks)
#pragma unroll
        for (int j = 0; j < 8; ++j) {
          unsigned short h = f2bf_rne(va[ks][j]);
          ah[ks][j] = (short)h;
          al[ks][j] = (short)f2bf_rne(va[ks][j] - bf2f(h));
        }
      acc[0] = (f32x4){0.f, 0.f, 0.f, 0.f};
      acc[1] = (f32x4){0.f, 0.f, 0.f, 0.f};
#pragma unroll
      for (int ks = 0; ks < 4; ++ks)
#pragma unroll
        for (int ct = 0; ct < 2; ++ct) {
          acc[ct] = __builtin_amdgcn_mfma_f32_16x16x32_bf16(ah[ks], B1h_[ct][ks], acc[ct], 0, 0, 0);
          acc[ct] = __builtin_amdgcn_mfma_f32_16x16x32_bf16(ah[ks], B1l_[ct][ks], acc[ct], 0, 0, 0);
          acc[ct] = __builtin_amdgcn_mfma_f32_16x16x32_bf16(al[ks], B1h_[ct][ks], acc[ct], 0, 0, 0);
        }
    }
    // ---- h -> LDS
    __syncthreads();
#pragma unroll
    for (int ct = 0; ct < 2; ++ct) {
      const float bb = ct ? b1v1 : b1v0;
      const int col = (w * 2 + ct) * 16 + lr;
#pragma unroll
      for (int q = 0; q < 4; ++q)
        hl[kg * 4 + q][col] = fmaxf(acc[ct][q] + bb, 0.f);
    }
    __syncthreads();
    // ---- GEMM2: A from LDS
    {
      float va[4][8];
#pragma unroll
      for (int ks = 0; ks < 4; ++ks) {
        *(float4*)&va[ks][0] = *(const float4*)&hl[lr][ks * 32 + kg * 8];
        *(float4*)&va[ks][4] = *(const float4*)&hl[lr][ks * 32 + kg * 8 + 4];
      }
      short8 ah[4], al[4];
#pragma unroll
      for (int ks = 0; ks < 4; ++ks)
#pragma unroll
        for (int j = 0; j < 8; ++j) {
          unsigned short h = f2bf_rne(va[ks][j]);
          ah[ks][j] = (short)h;
          al[ks][j] = (short)f2bf_rne(va[ks][j] - bf2f(h));
        }
      acc[0] = (f32x4){0.f, 0.f, 0.f, 0.f};
      acc[1] = (f32x4){0.f, 0.f, 0.f, 0.f};
#pragma unroll
      for (int ks = 0; ks < 4; ++ks)
#pragma unroll
        for (int ct = 0; ct < 2; ++ct) {
          acc[ct] = __builtin_amdgcn_mfma_f32_16x16x32_bf16(ah[ks], B2h_[ct][ks], acc[ct], 0, 0, 0);
          acc[ct] = __builtin_amdgcn_mfma_f32_16x16x32_bf16(ah[ks], B2l_[ct][ks], acc[ct], 0, 0, 0);
          acc[ct] = __builtin_amdgcn_mfma_f32_16x16x32_bf16(al[ks], B2h_[ct][ks], acc[ct], 0, 0, 0);
        }
    }
    // ---- epilogue
#pragma unroll
    for (int ct = 0; ct < 2; ++ct) {
      const float bb = ct ? b2v1 : b2v0;
      const int col = (w * 2 + ct) * 16 + lr;
#pragma unroll
      for (int q = 0; q < 4; ++q) {
        const float v = fmaxf(acc[ct][q] + bb, 0.f);
        const size_t r = (size_t)c * 16 + kg * 4 + q;
        if (F32OUT) out[r * DD + col] = v;
        if (BFOUT) outbf[r * DD + col] = f2bf_rne(v);
      }
    }
  }
}

// ------------------------------------------------- fused predictor GEMMs
// P1, P2 BOTH stored bf16; no aliasing, no barrier.
__global__ __launch_bounds__(256) void gemm_pred2(
    const float* __restrict__ in,
    const unsigned short* __restrict__ W1h, const unsigned short* __restrict__ W1l,
    const unsigned short* __restrict__ W2h, const unsigned short* __restrict__ W2l,
    const float* __restrict__ bp1,
    unsigned short* __restrict__ P1bf, unsigned short* __restrict__ P2bf) {
  const int t = threadIdx.x;
  const int w = t >> 6, l = t & 63;
  const int lr = l & 15, kg = l >> 4;

  short8 B1h[2][4], B1l[2][4], B2h[2][4], B2l[2][4];
#pragma unroll
  for (int ct = 0; ct < 2; ++ct)
#pragma unroll
    for (int ks = 0; ks < 4; ++ks) {
      const size_t bo = (size_t)((w * 2 + ct) * 16 + lr) * DD + ks * 32 + kg * 8;
      B1h[ct][ks] = *(const short8*)(W1h + bo);
      B1l[ct][ks] = *(const short8*)(W1l + bo);
      B2h[ct][ks] = *(const short8*)(W2h + bo);
      B2l[ct][ks] = *(const short8*)(W2l + bo);
    }
  float bv0 = bp1[(w * 2 + 0) * 16 + lr];
  float bv1 = bp1[(w * 2 + 1) * 16 + lr];

  for (int c = blockIdx.x; c < NN / 16; c += gridDim.x) {
    const float* ap = in + ((size_t)c * 16 + lr) * DD + kg * 8;
    float va[4][8];
#pragma unroll
    for (int ks = 0; ks < 4; ++ks) {
      *(float4*)&va[ks][0] = *(const float4*)(ap + ks * 32);
      *(float4*)&va[ks][4] = *(const float4*)(ap + ks * 32 + 4);
    }
    short8 ah[4], al[4];
#pragma unroll
    for (int ks = 0; ks < 4; ++ks)
#pragma unroll
      for (int j = 0; j < 8; ++j) {
        unsigned short h = f2bf_rne(va[ks][j]);
        ah[ks][j] = (short)h;
        al[ks][j] = (short)f2bf_rne(va[ks][j] - bf2f(h));
      }
    f32x4 acc1[2], acc2[2];
    acc1[0] = (f32x4){0.f, 0.f, 0.f, 0.f};
    acc1[1] = (f32x4){0.f, 0.f, 0.f, 0.f};
    acc2[0] = (f32x4){0.f, 0.f, 0.f, 0.f};
    acc2[1] = (f32x4){0.f, 0.f, 0.f, 0.f};
#pragma unroll
    for (int ks = 0; ks < 4; ++ks) {
#pragma unroll
      for (int ct = 0; ct < 2; ++ct) {
        acc1[ct] = __builtin_amdgcn_mfma_f32_16x16x32_bf16(ah[ks], B1h[ct][ks], acc1[ct], 0, 0, 0);
        acc1[ct] = __builtin_amdgcn_mfma_f32_16x16x32_bf16(ah[ks], B1l[ct][ks], acc1[ct], 0, 0, 0);
        acc1[ct] = __builtin_amdgcn_mfma_f32_16x16x32_bf16(al[ks], B1h[ct][ks], acc1[ct], 0, 0, 0);
        acc2[ct] = __builtin_amdgcn_mfma_f32_16x16x32_bf16(ah[ks], B2h[ct][ks], acc2[ct], 0, 0, 0);
        acc2[ct] = __builtin_amdgcn_mfma_f32_16x16x32_bf16(ah[ks], B2l[ct][ks], acc2[ct], 0, 0, 0);
        acc2[ct] = __builtin_amdgcn_mfma_f32_16x16x32_bf16(al[ks], B2h[ct][ks], acc2[ct], 0, 0, 0);
      }
    }
#pragma unroll
    for (int ct = 0; ct < 2; ++ct) {
      const int col = (w * 2 + ct) * 16 + lr;
      const float bb = ct ? bv1 : bv0;
#pragma unroll
      for (int q4 = 0; q4 < 4; ++q4) {
        const size_t r = (size_t)c * 16 + kg * 4 + q4;
        P1bf[r * DD + col] = f2bf_rne(acc1[ct][q4]);
        P2bf[r * DD + col] = f2bf_rne(acc2[ct][q4] + bb);
      }
    }
  }
}

// ------------------------------------------------- final edge pass (node-parallel)
__global__ __launch_bounds__(256) void edge_out(
    const unsigned short* __restrict__ P1bf, const unsigned short* __restrict__ P2bf,
    const int* __restrict__ offs, const int4* __restrict__ recs,
    const float4* __restrict__ Wp2_4,
    const float* __restrict__ bp2, float* __restrict__ out) {
  const int slot = threadIdx.x >> 5, lane = threadIdx.x & 31;
  const int n = blockIdx.x * 8 + slot;
  if (n >= NN) return;
  const float4 w = Wp2_4[lane];
  const float bb = bp2[0];
  const uint2 pq = *(const uint2*)(P2bf + (size_t)n * DD + lane * 4);
  float4 p2;
  p2.x = __uint_as_float(pq.x << 16);
  p2.y = __uint_as_float(pq.x & 0xffff0000u);
  p2.z = __uint_as_float(pq.y << 16);
  p2.w = __uint_as_float(pq.y & 0xffff0000u);
  const int beg = offs[n], end = offs[n + 1];
  int i = beg;
#define EDGEV(vv, qq)                                                         \
  {                                                                           \
    const float q0 = __uint_as_float((qq).x << 16);                           \
    const float q1 = __uint_as_float((qq).x & 0xffff0000u);                   \
    const float q2 = __uint_as_float((qq).y << 16);                           \
    const float q3 = __uint_as_float((qq).y & 0xffff0000u);                   \
    vv = fmaxf(q0 + p2.x, 0.f) * w.x + fmaxf(q1 + p2.y, 0.f) * w.y            \
       + fmaxf(q2 + p2.z, 0.f) * w.z + fmaxf(q3 + p2.w, 0.f) * w.w;           \
  }
  for (; i + 8 <= end; i += 8) {
    int4 r[8];
#pragma unroll
    for (int u = 0; u < 8; ++u) r[u] = recs[i + u];
    uint2 q[8];
#pragma unroll
    for (int u = 0; u < 8; ++u)
      q[u] = *(const uint2*)(P1bf + (size_t)r[u].x * DD + lane * 4);
    float v[8];
#pragma unroll
    for (int u = 0; u < 8; ++u) EDGEV(v[u], q[u])
#pragma unroll
    for (int m = 16; m >= 1; m >>= 1) {
#pragma unroll
      for (int u = 0; u < 8; ++u) v[u] += __shfl_xor(v[u], m, 64);
    }
    if (lane == 0) {
#pragma unroll
      for (int u = 0; u < 8; ++u) out[r[u].y] = v[u] + bb;
    }
  }
  for (; i + 4 <= end; i += 4) {
    int4 r[4];
#pragma unroll
    for (int u = 0; u < 4; ++u) r[u] = recs[i + u];
    uint2 q[4];
#pragma unroll
    for (int u = 0; u < 4; ++u)
      q[u] = *(const uint2*)(P1bf + (size_t)r[u].x * DD + lane * 4);
    float v[4];
#pragma unroll
    for (int u = 0; u < 4; ++u) EDGEV(v[u], q[u])
#pragma unroll
    for (int m = 16; m >= 1; m >>= 1) {
#pragma unroll
      for (int u = 0; u < 4; ++u) v[u] += __shfl_xor(v[u], m, 64);
    }
    if (lane == 0) {
#pragma unroll
      for (int u = 0; u < 4; ++u) out[r[u].y] = v[u] + bb;
    }
  }
  for (; i < end; ++i) {
    const int4 rec = recs[i];
    const uint2 qq = *(const uint2*)(P1bf + (size_t)rec.x * DD + lane * 4);
    float v;
    EDGEV(v, qq)
#pragma unroll
    for (int m = 16; m >= 1; m >>= 1) v += __shfl_xor(v, m, 64);
    if (lane == 0) out[rec.y] = v + bb;
  }
#undef EDGEV
}

// ---------------------------------------------------------------- launch
extern "C" void kernel_launch(void* const* d_in, const int* in_sizes, int n_in,
                              void* d_out, int out_size, void* d_ws, size_t ws_size,
                              hipStream_t stream) {
  const float* x_in = (const float*)d_in[0];
  const float* ea   = (const float*)d_in[1];
  const int*   ei   = (const int*)d_in[2];   // integer inputs arrive as int32
  const float* Wl1 = (const float*)d_in[3];
  const float* bl1 = (const float*)d_in[4];
  const float* Wl2 = (const float*)d_in[5];
  const float* bl2 = (const float*)d_in[6];
  const float* We  = (const float*)d_in[7];
  const float* be  = (const float*)d_in[8];
  const float* Wp1 = (const float*)d_in[9];
  const float* bp1 = (const float*)d_in[10];
  const float* Wp2 = (const float*)d_in[11];
  const float* bp2 = (const float*)d_in[12];
  const int* src = ei;
  const int* dst = ei + NE;

  // workspace layout (~81 MB)
  float* bufA   = (float*)d_ws;                    // NN*DD f32
  float* bufB   = bufA + (size_t)NN * DD;          // NN*DD f32
  int*   cnt    = (int*)(bufB + (size_t)NN * DD);  // NN
  int*   offs   = cnt + NN;                        // NN+1
  int*   rank   = offs + NN + 1;                   // NE
  int4*  recs   = (int4*)(((uintptr_t)(rank + NE) + 15) & ~(uintptr_t)15); // NE
  unsigned short* WTh = (unsigned short*)(recs + NE);   // 8*16384 bf16
  unsigned short* WTl = WTh + 8 * 16384;                // 8*16384 bf16
  unsigned short* xbf = WTl + 8 * 16384;                // NN*DD bf16 (x_l / P2bf)

  // fused prologue + CSR build (per-launch, deterministic)
  prologue<<<(NN * DD / 2 + 255) / 256, 256, 0, stream>>>(
      Wl1, Wl2, Wp1, WTh, WTl, (const float2*)x_in, (unsigned*)xbf, cnt);
  hist_rank<<<NE / 256, 256, 0, stream>>>(dst, cnt, rank);
  scan_nodes<<<1, 1024, 0, stream>>>(cnt, offs);
  csr_fill<<<NE / 256, 256, 0, stream>>>(src, dst, ea, offs, rank, recs);

  const int GB = 1024;            // gemm grid: ~3 chunks/block
  const int AB = (NN + 7) / 8;    // 6250 blocks: 1 node/slot (max TLP)
#define WH(g) (WTh + (size_t)(g) * 16384)
#define WL(g) (WTl + (size_t)(g) * 16384)

  // L0: agg(xbf=x0)->A; mlp A -> xbf (x1, bf16 only)
  aggregate<<<AB, 256, 0, stream>>>(
      xbf, offs, recs, (const float4*)We, (const float4*)be, bufA);
  fused_mlp<false, true><<<GB, 256, 0, stream>>>(
      bufA, WH(0), WL(0), WH(3), WL(3), bl1, bl2, nullptr, xbf);
  // L1: agg(xbf=x1)->A; mlp A -> xbf (x2, bf16 only)
  aggregate<<<AB, 256, 0, stream>>>(
      xbf, offs, recs, (const float4*)(We + DD), (const float4*)(be + DD), bufA);
  fused_mlp<false, true><<<GB, 256, 0, stream>>>(
      bufA, WH(1), WL(1), WH(4), WL(4), bl1 + DD, bl2 + DD, nullptr, xbf);
  // L2: agg(xbf=x2)->A; mlp A -> bufB (f32, feeds pred)
  aggregate<<<AB, 256, 0, stream>>>(
      xbf, offs, recs, (const float4*)(We + 2 * DD), (const float4*)(be + 2 * DD), bufA);
  fused_mlp<true, false><<<GB, 256, 0, stream>>>(
      bufA, WH(2), WL(2), WH(5), WL(5), bl1 + 2 * DD, bl2 + 2 * DD, bufB, nullptr);
  // predictor: xf = bufB.  P1bf -> bufA storage; P2bf -> xbf.
  gemm_pred2<<<GB, 256, 0, stream>>>(bufB, WH(6), WL(6), WH(7), WL(7), bp1,
                                     (unsigned short*)bufA, xbf);
  edge_out<<<AB, 256, 0, stream>>>(
      (const unsigned short*)bufA, xbf, offs, recs,
      (const float4*)Wp2, bp2, (float*)d_out);
}